// Round 3
// baseline (877.008 us; speedup 1.0000x reference)
//
#include <hip/hip_runtime.h>
#include <hip/hip_bf16.h>

// Problem constants
constexpr int Bc  = 4;
constexpr int Sc  = 2048;
constexpr int Dc  = 1024;
constexpr int Hc  = 16;
constexpr int DKc = 64;
constexpr int Mc  = Bc * Sc;      // 8192 token rows

typedef __bf16 bf16x8 __attribute__((ext_vector_type(8)));
typedef __bf16 bf16x4 __attribute__((ext_vector_type(4)));
typedef float  f32x4  __attribute__((ext_vector_type(4)));
typedef unsigned short ushort_t;

#define DEV __device__ __forceinline__

DEV unsigned short f2bf(float f) {
    unsigned u = __builtin_bit_cast(unsigned, f);
    u += 0x7FFFu + ((u >> 16) & 1u);            // RNE
    return (unsigned short)(u >> 16);
}
DEV unsigned pack2(float a, float b) {
    return (unsigned)f2bf(a) | ((unsigned)f2bf(b) << 16);
}

// ---------------------------------------------------------------------------
// Fold na_w into projection weights: out[h*DK+i][j] = sum_t na[i][t]*w[h*DK+t][j]
__global__ __launch_bounds__(256) void fold_w(const float* __restrict__ na,
                                              const float* __restrict__ w,
                                              unsigned short* __restrict__ out) {
    int idx = blockIdx.x * 256 + threadIdx.x;   // 0 .. D*D-1
    int col = idx & (Dc - 1);
    int row = idx >> 10;
    int h = row >> 6, i = row & 63;
    float acc = 0.f;
#pragma unroll 8
    for (int t = 0; t < DKc; ++t)
        acc += na[i * DKc + t] * w[(h * DKc + t) * Dc + col];
    out[idx] = f2bf(acc);
}

__global__ __launch_bounds__(256) void conv_w(const float* __restrict__ w,
                                              unsigned short* __restrict__ out) {
    int i = blockIdx.x * 256 + threadIdx.x;
    out[i] = f2bf(w[i]);
}

__global__ __launch_bounds__(256) void fold_b(const float* __restrict__ na,
                                              const float* __restrict__ b,
                                              const float* __restrict__ nb,
                                              float* __restrict__ out) {
    int idx = blockIdx.x * 256 + threadIdx.x;
    if (idx >= Dc) return;
    int h = idx >> 6, i = idx & 63;
    float acc = nb[i];
    for (int t = 0; t < DKc; ++t) acc += na[i * DKc + t] * b[h * DKc + t];
    out[idx] = acc;
}

// Pack int32 mask -> bitmask (bit=1 keep). One thread per element, ballot per wave.
__global__ __launch_bounds__(256) void pack_mask(const int* __restrict__ m,
                                                 unsigned* __restrict__ out) {
    size_t gid = (size_t)blockIdx.x * 256 + threadIdx.x;
    int v = m[gid];
    unsigned long long bal = __ballot(v != 0);
    int lane = threadIdx.x & 63;
    if (lane == 0)       out[gid >> 5] = (unsigned)bal;
    else if (lane == 32) out[gid >> 5] = (unsigned)(bal >> 32);
}

// ---------------------------------------------------------------------------
// Generic 128x128x(K) GEMM, C = A * B^T (+bias, epilogue variants).
// EPI 0: tanh(acc+bias[col]) [*log2e/(8*temp[h]) if scaled] -> bf16 [B,H,S,DK]
// EPI 1: acc+bias[row]       -> bf16 vT layout   [B,H,DK,S]
// EPI 2: acc+bias[col]       -> fp32 merged      [M,N]
// MERGE: blockIdx.z==1 switches to the second (A,B,bias,out) set, unscaled.
template <bool AF32, bool BF32, int EPI, bool MERGE = false>
__global__ __launch_bounds__(256) void gemm_k(const void* __restrict__ Ap,
                                              const void* __restrict__ Bp,
                                              const float* __restrict__ bias,
                                              void* __restrict__ outp,
                                              int Mdim, int Ndim, int Kdim,
                                              const void* __restrict__ Ap2,
                                              const void* __restrict__ Bp2,
                                              const float* __restrict__ bias2,
                                              void* __restrict__ outp2,
                                              const float* __restrict__ temp) {
    constexpr int BK = 64;
    __shared__ unsigned char As[128 * 128];  // 128 rows x 128B (64 bf16)
    __shared__ unsigned char Bs[128 * 128];

    bool doScale = (temp != nullptr);
    if constexpr (MERGE) {
        if (blockIdx.z == 1) { Ap = Ap2; Bp = Bp2; bias = bias2; outp = outp2; doScale = false; }
    }

    const int tid = threadIdx.x, lane = tid & 63, wave = tid >> 6;
    const int wr = wave >> 1, wc = wave & 1;
    const int m0 = blockIdx.y * 128, n0 = blockIdx.x * 128;

    f32x4 acc[4][4] = {};

    const int nK = Kdim / BK;
    for (int kt = 0; kt < nK; ++kt) {
        const int k0 = kt * BK;
        float4 afr[8]; uint4 abr[4];
        float4 bfr[8]; uint4 bbr[4];
        if constexpr (AF32) {
            const float* A = (const float*)Ap;
            const int c4 = tid & 15;
#pragma unroll
            for (int i = 0; i < 8; ++i) {
                int row = (tid >> 4) + 16 * i;
                afr[i] = *(const float4*)(A + (size_t)(m0 + row) * Kdim + k0 + c4 * 4);
            }
        } else {
            const unsigned short* A = (const unsigned short*)Ap;
            const int c8 = tid & 7;
#pragma unroll
            for (int i = 0; i < 4; ++i) {
                int row = (tid >> 3) + 32 * i;
                abr[i] = *(const uint4*)(A + (size_t)(m0 + row) * Kdim + k0 + c8 * 8);
            }
        }
        if constexpr (BF32) {
            const float* Bm = (const float*)Bp;
            const int c4 = tid & 15;
#pragma unroll
            for (int i = 0; i < 8; ++i) {
                int row = (tid >> 4) + 16 * i;
                bfr[i] = *(const float4*)(Bm + (size_t)(n0 + row) * Kdim + k0 + c4 * 4);
            }
        } else {
            const unsigned short* Bm = (const unsigned short*)Bp;
            const int c8 = tid & 7;
#pragma unroll
            for (int i = 0; i < 4; ++i) {
                int row = (tid >> 3) + 32 * i;
                bbr[i] = *(const uint4*)(Bm + (size_t)(n0 + row) * Kdim + k0 + c8 * 8);
            }
        }
        __syncthreads();   // previous tile's LDS reads complete
        if constexpr (AF32) {
            const int colb = (tid & 15) * 8;
#pragma unroll
            for (int i = 0; i < 8; ++i) {
                int row = (tid >> 4) + 16 * i;
                uint2 u; u.x = pack2(afr[i].x, afr[i].y); u.y = pack2(afr[i].z, afr[i].w);
                *(uint2*)(As + row * 128 + (colb ^ ((row & 7) << 4))) = u;
            }
        } else {
            const int colb = (tid & 7) * 16;
#pragma unroll
            for (int i = 0; i < 4; ++i) {
                int row = (tid >> 3) + 32 * i;
                *(uint4*)(As + row * 128 + (colb ^ ((row & 7) << 4))) = abr[i];
            }
        }
        if constexpr (BF32) {
            const int colb = (tid & 15) * 8;
#pragma unroll
            for (int i = 0; i < 8; ++i) {
                int row = (tid >> 4) + 16 * i;
                uint2 u; u.x = pack2(bfr[i].x, bfr[i].y); u.y = pack2(bfr[i].z, bfr[i].w);
                *(uint2*)(Bs + row * 128 + (colb ^ ((row & 7) << 4))) = u;
            }
        } else {
            const int colb = (tid & 7) * 16;
#pragma unroll
            for (int i = 0; i < 4; ++i) {
                int row = (tid >> 3) + 32 * i;
                *(uint4*)(Bs + row * 128 + (colb ^ ((row & 7) << 4))) = bbr[i];
            }
        }
        __syncthreads();
#pragma unroll
        for (int s = 0; s < 2; ++s) {
            const int cb = s * 64 + (lane >> 4) * 16;
            bf16x8 a[4], b[4];
#pragma unroll
            for (int m = 0; m < 4; ++m) {
                int row = wr * 64 + m * 16 + (lane & 15);
                a[m] = *(const bf16x8*)(As + row * 128 + (cb ^ ((row & 7) << 4)));
            }
#pragma unroll
            for (int n = 0; n < 4; ++n) {
                int row = wc * 64 + n * 16 + (lane & 15);
                b[n] = *(const bf16x8*)(Bs + row * 128 + (cb ^ ((row & 7) << 4)));
            }
#pragma unroll
            for (int m = 0; m < 4; ++m)
#pragma unroll
                for (int n = 0; n < 4; ++n)
                    acc[m][n] = __builtin_amdgcn_mfma_f32_16x16x32_bf16(a[m], b[n], acc[m][n], 0, 0, 0);
        }
    }

    // Epilogue. C/D layout: row=(lane>>4)*4+r, col=lane&15.
#pragma unroll
    for (int m = 0; m < 4; ++m)
#pragma unroll
        for (int n = 0; n < 4; ++n) {
            int gn = n0 + wc * 64 + n * 16 + (lane & 15);
            float sc_h = 1.f;
            if constexpr (EPI == 0) {
                if (doScale) sc_h = 0.18033688011112042f * __builtin_amdgcn_rcpf(temp[gn >> 6]);
            }
#pragma unroll
            for (int r = 0; r < 4; ++r) {
                int gm = m0 + wr * 64 + m * 16 + ((lane >> 4) << 2) + r;
                float v = acc[m][n][r];
                if constexpr (EPI == 0) {
                    v = tanhf(v + bias[gn]) * sc_h;
                    int b = gm >> 11, s = gm & 2047, hh = gn >> 6, dk = gn & 63;
                    ((unsigned short*)outp)[(((size_t)(b * Hc + hh)) * Sc + s) * DKc + dk] = f2bf(v);
                } else if constexpr (EPI == 1) {
                    v += bias[gm];
                    int hh = gm >> 6, dk = gm & 63, b = gn >> 11, s = gn & 2047;
                    ((unsigned short*)outp)[(((size_t)(b * Hc + hh)) * DKc + dk) * Sc + s] = f2bf(v);
                } else {
                    v += bias[gn];
                    ((float*)outp)[(size_t)gm * Ndim + gn] = v;
                }
            }
        }
}

// ---------------------------------------------------------------------------
// Flash attention, barrier-free. Grid: 1024 blocks (XCD-swizzled), 512 threads
// (8 independent waves, 16 q-rows each; block covers 128 q-rows of one (b,h)).
// K and V^T are read directly from global (L1/L2-cached; each XCD owns whole
// (b,h) pairs via the swizzle). Only LDS use: per-wave P round-trip buffer.
// Scores arrive pre-scaled by log2e/(8*temp[h]) (folded into qn), so softmax
// runs in base-2: exp2 direct, defer-max threshold 12 (e <= 4096, bf16-safe).
__global__ __launch_bounds__(512) void attn_k(const ushort_t* __restrict__ qn,
                                              const ushort_t* __restrict__ kn,
                                              const ushort_t* __restrict__ vt,
                                              const unsigned* __restrict__ mbits,
                                              ushort_t* __restrict__ ctxb) {
    __shared__ __align__(16) unsigned char Ps[8][16 * 256];   // per-wave P [q:16][k:128] bf16

    const int tid = threadIdx.x, lane = tid & 63, wave = tid >> 6;
    const int q = lane & 15, g = lane >> 4;

    // bijective XCD swizzle: XCD x gets orig ids [x*128, x*128+128) = one b, 8 heads
    const int wg = blockIdx.x;
    const int orig = (wg & 7) * 128 + (wg >> 3);
    const int qt = orig & 15, h = (orig >> 4) & 15, b = orig >> 8;
    const int q0 = qt * 128;
    const int qrow = q0 + wave * 16 + q;
    const size_t headoff = ((size_t)(b * Hc + h)) * Sc * DKc;

    const ushort_t* Kbase = kn + headoff + (size_t)q * DKc + g * 8;   // + krow*64
    const ushort_t* Vbase = vt + headoff + (size_t)q * Sc + g * 8;    // + j*16*Sc + k

    bf16x8 qf0, qf1;
    {
        const ushort_t* p = qn + headoff + (size_t)qrow * DKc + g * 8;
        qf0 = *(const bf16x8*)p;
        qf1 = *(const bf16x8*)(p + 32);
    }
    const unsigned* mrow = mbits + ((size_t)b * Sc + qrow) * (Sc / 32);

    f32x4 ctxa[4] = {};
    float m_run = -1e30f, l_run = 0.f;
    unsigned char* pb = Ps[wave];
    const int swz = (q & 7) << 4;

    for (int kt = 0; kt < Sc / 128; ++kt) {
        // ---- QK^T: 128 k-rows x 16 q, direct-global K frags
        f32x4 sc[8] = {};
        const ushort_t* Kt = Kbase + (size_t)kt * 128 * DKc;
        unsigned mw[4];
#pragma unroll
        for (int j = 0; j < 4; ++j) mw[j] = mrow[kt * 4 + j];
        __builtin_amdgcn_s_setprio(1);
#pragma unroll
        for (int f = 0; f < 8; ++f) {
            bf16x8 a0 = *(const bf16x8*)(Kt + (size_t)f * 16 * DKc);
            bf16x8 a1 = *(const bf16x8*)(Kt + (size_t)f * 16 * DKc + 32);
            sc[f] = __builtin_amdgcn_mfma_f32_16x16x32_bf16(a0, qf0, sc[f], 0, 0, 0);
            sc[f] = __builtin_amdgcn_mfma_f32_16x16x32_bf16(a1, qf1, sc[f], 0, 0, 0);
        }
        __builtin_amdgcn_s_setprio(0);

        // ---- online softmax in base-2, max over raw (unmasked) scores
        float tmax = -1e30f;
#pragma unroll
        for (int f = 0; f < 8; ++f) {
            float m01 = fmaxf(sc[f][0], sc[f][1]);
            float m23 = fmaxf(sc[f][2], sc[f][3]);
            tmax = fmaxf(tmax, fmaxf(m01, m23));
        }
        tmax = fmaxf(tmax, __shfl_xor(tmax, 16));
        tmax = fmaxf(tmax, __shfl_xor(tmax, 32));
        if (!__all(tmax - m_run <= 12.f)) {          // defer-max (base-2 THR=12)
            float newm = fmaxf(m_run, tmax);
            float alpha = __builtin_amdgcn_exp2f(m_run - newm);
            l_run *= alpha;
            float al[4];
#pragma unroll
            for (int r = 0; r < 4; ++r) al[r] = __shfl(alpha, (g << 2) + r);
#pragma unroll
            for (int j = 0; j < 4; ++j)
#pragma unroll
                for (int r = 0; r < 4; ++r) ctxa[j][r] *= al[r];
            m_run = newm;
        }
        float tsum = 0.f;
#pragma unroll
        for (int f = 0; f < 8; ++f) {
            unsigned w = mw[f >> 1];
#pragma unroll
            for (int r = 0; r < 4; ++r) {
                int bit = ((f & 1) << 4) + (g << 2) + r;
                float e = __builtin_amdgcn_exp2f(sc[f][r] - m_run);
                e = ((w >> bit) & 1u) ? e : 0.f;
                sc[f][r] = e;
                tsum += e;
            }
        }
        tsum += __shfl_xor(tsum, 16);
        tsum += __shfl_xor(tsum, 32);
        l_run += tsum;

        // ---- pack P to bf16, per-wave LDS (flat-k layout, XOR-swizzled)
#pragma unroll
        for (int f = 0; f < 8; ++f) {
            bf16x4 t;
            t[0] = (__bf16)sc[f][0]; t[1] = (__bf16)sc[f][1];
            t[2] = (__bf16)sc[f][2]; t[3] = (__bf16)sc[f][3];
            *(bf16x4*)(pb + q * 256 + ((f * 32 + g * 8) ^ swz)) = t;
        }

        // ---- PV: ctx[q][d] += P[q][k] * V^T[d][k], V direct-global
        const ushort_t* Vt = Vbase + kt * 128;
        __builtin_amdgcn_s_setprio(1);
#pragma unroll
        for (int cs = 0; cs < 4; ++cs) {
            bf16x8 pa = *(const bf16x8*)(pb + q * 256 + ((cs * 64 + g * 16) ^ swz));
#pragma unroll
            for (int j = 0; j < 4; ++j) {
                bf16x8 vb = *(const bf16x8*)(Vt + (size_t)j * 16 * Sc + cs * 32);
                ctxa[j] = __builtin_amdgcn_mfma_f32_16x16x32_bf16(pa, vb, ctxa[j], 0, 0, 0);
            }
        }
        __builtin_amdgcn_s_setprio(0);
    }

    // ---- epilogue: normalize by row-sum of accumulator's own q, write bf16 ctx
    float lv[4];
#pragma unroll
    for (int r = 0; r < 4; ++r) {
        float lr = __shfl(l_run, (g << 2) + r);
        lv[r] = __builtin_amdgcn_rcpf(lr);
    }
#pragma unroll
    for (int j = 0; j < 4; ++j)
#pragma unroll
        for (int r = 0; r < 4; ++r) {
            int srow = q0 + wave * 16 + (g << 2) + r;
            int col = h * DKc + j * 16 + q;
            float v = ctxa[j][r] * lv[r];
            ctxb[((size_t)b * Sc + srow) * Dc + col] = __builtin_bit_cast(unsigned short, (__bf16)v);
        }
}

// ---------------------------------------------------------------------------
__global__ __launch_bounds__(256) void rmsnorm_k(float* __restrict__ out,
                                                 const float* __restrict__ w) {
    const int row = blockIdx.x, tid = threadIdx.x;
    float4* p = (float4*)(out + (size_t)row * Dc) + tid;
    float4 v = *p;
    float ss = v.x * v.x + v.y * v.y + v.z * v.z + v.w * v.w;
#pragma unroll
    for (int o = 32; o >= 1; o >>= 1) ss += __shfl_xor(ss, o);
    __shared__ float sm[4];
    if ((tid & 63) == 0) sm[tid >> 6] = ss;
    __syncthreads();
    float tot = sm[0] + sm[1] + sm[2] + sm[3];
    float r = rsqrtf(tot * (1.f / Dc) + 1e-8f);
    float4 wv = *((const float4*)w + tid);
    v.x *= r * wv.x; v.y *= r * wv.y; v.z *= r * wv.z; v.w *= r * wv.w;
    *p = v;
}

// ---------------------------------------------------------------------------
extern "C" void kernel_launch(void* const* d_in, const int* in_sizes, int n_in,
                              void* d_out, int out_size, void* d_ws, size_t ws_size,
                              hipStream_t stream) {
    (void)in_sizes; (void)n_in; (void)out_size; (void)ws_size;
    const float* Q    = (const float*)d_in[0];
    const float* K    = (const float*)d_in[1];
    const float* V    = (const float*)d_in[2];
    const int*   mask = (const int*)  d_in[3];
    const float* wq   = (const float*)d_in[4];
    const float* bq   = (const float*)d_in[5];
    const float* wk   = (const float*)d_in[6];
    const float* bk   = (const float*)d_in[7];
    const float* wv   = (const float*)d_in[8];
    const float* bv   = (const float*)d_in[9];
    const float* wo   = (const float*)d_in[10];
    const float* bo   = (const float*)d_in[11];
    const float* naqw = (const float*)d_in[12];
    const float* naqb = (const float*)d_in[13];
    const float* nakw = (const float*)d_in[14];
    const float* nakb = (const float*)d_in[15];
    const float* temp = (const float*)d_in[16];
    const float* rmsw = (const float*)d_in[17];

    char* ws = (char*)d_ws;
    size_t off = 0;
    auto take = [&](size_t n) { char* p = ws + off; off += (n + 255) & ~(size_t)255; return p; };
    unsigned short* qnb  = (unsigned short*)take((size_t)Mc * Dc * 2);
    unsigned short* knb  = (unsigned short*)take((size_t)Mc * Dc * 2);
    unsigned short* vtb  = (unsigned short*)take((size_t)Mc * Dc * 2);
    unsigned short* ctxb = (unsigned short*)take((size_t)Mc * Dc * 2);
    unsigned short* wqf  = (unsigned short*)take((size_t)Dc * Dc * 2);
    unsigned short* wkf  = (unsigned short*)take((size_t)Dc * Dc * 2);
    unsigned short* wvf  = (unsigned short*)take((size_t)Dc * Dc * 2);
    unsigned short* wof  = (unsigned short*)take((size_t)Dc * Dc * 2);
    float*    bqf   = (float*)take(Dc * 4);
    float*    bkf   = (float*)take(Dc * 4);
    unsigned* mbits = (unsigned*)take((size_t)Bc * Sc * (Sc / 32) * 4);

    fold_w<<<dim3(Dc * Dc / 256), 256, 0, stream>>>(naqw, wq, wqf);
    fold_w<<<dim3(Dc * Dc / 256), 256, 0, stream>>>(nakw, wk, wkf);
    conv_w<<<dim3(Dc * Dc / 256), 256, 0, stream>>>(wv, wvf);
    conv_w<<<dim3(Dc * Dc / 256), 256, 0, stream>>>(wo, wof);
    fold_b<<<dim3((Dc + 255) / 256), 256, 0, stream>>>(naqw, bq, naqb, bqf);
    fold_b<<<dim3((Dc + 255) / 256), 256, 0, stream>>>(nakw, bk, nakb, bkf);
    pack_mask<<<dim3(Bc * Sc * Sc / 256), 256, 0, stream>>>(mask, mbits);

    // merged Q/K projections: z=0 -> qn (tanh, scaled by log2e/(8*temp)); z=1 -> kn (tanh)
    gemm_k<true, false, 0, true><<<dim3(Dc / 128, Mc / 128, 2), 256, 0, stream>>>(
        Q, wqf, bqf, qnb, Mc, Dc, Dc, K, wkf, bkf, knb, temp);
    // v^T = Wv @ V_in^T + bv  (bf16, [B,H,DK,S])
    gemm_k<false, true, 1><<<dim3(Mc / 128, Dc / 128), 256, 0, stream>>>(
        wvf, V, bv, vtb, Dc, Mc, Dc, nullptr, nullptr, nullptr, nullptr, nullptr);

    attn_k<<<dim3(1024), 512, 0, stream>>>(qnb, knb, vtb, mbits, ctxb);

    // out = ctx @ wo^T + bo (fp32 into d_out), then in-place RMSNorm
    gemm_k<false, false, 2><<<dim3(Dc / 128, Mc / 128), 256, 0, stream>>>(
        ctxb, wof, bo, d_out, Mc, Dc, Dc, nullptr, nullptr, nullptr, nullptr, nullptr);
    rmsnorm_k<<<dim3(Mc), 256, 0, stream>>>((float*)d_out, rmsw);
}

// Round 4
// 831.258 us; speedup vs baseline: 1.0550x; 1.0550x over previous
//
#include <hip/hip_runtime.h>
#include <hip/hip_bf16.h>

// Problem constants
constexpr int Bc  = 4;
constexpr int Sc  = 2048;
constexpr int Dc  = 1024;
constexpr int Hc  = 16;
constexpr int DKc = 64;
constexpr int Mc  = Bc * Sc;      // 8192 token rows

typedef __bf16 bf16x8 __attribute__((ext_vector_type(8)));
typedef __bf16 bf16x4 __attribute__((ext_vector_type(4)));
typedef float  f32x4  __attribute__((ext_vector_type(4)));
typedef unsigned short ushort_t;

#define DEV __device__ __forceinline__

DEV unsigned short f2bf(float f) {
    unsigned u = __builtin_bit_cast(unsigned, f);
    u += 0x7FFFu + ((u >> 16) & 1u);            // RNE
    return (unsigned short)(u >> 16);
}
DEV unsigned pack2(float a, float b) {
    return (unsigned)f2bf(a) | ((unsigned)f2bf(b) << 16);
}

// ---------------------------------------------------------------------------
__global__ __launch_bounds__(256) void fold_w(const float* __restrict__ na,
                                              const float* __restrict__ w,
                                              unsigned short* __restrict__ out) {
    int idx = blockIdx.x * 256 + threadIdx.x;   // 0 .. D*D-1
    int col = idx & (Dc - 1);
    int row = idx >> 10;
    int h = row >> 6, i = row & 63;
    float acc = 0.f;
#pragma unroll 8
    for (int t = 0; t < DKc; ++t)
        acc += na[i * DKc + t] * w[(h * DKc + t) * Dc + col];
    out[idx] = f2bf(acc);
}

__global__ __launch_bounds__(256) void conv_w(const float* __restrict__ w,
                                              unsigned short* __restrict__ out) {
    int i = blockIdx.x * 256 + threadIdx.x;
    out[i] = f2bf(w[i]);
}

__global__ __launch_bounds__(256) void fold_b(const float* __restrict__ na,
                                              const float* __restrict__ b,
                                              const float* __restrict__ nb,
                                              float* __restrict__ out) {
    int idx = blockIdx.x * 256 + threadIdx.x;
    if (idx >= Dc) return;
    int h = idx >> 6, i = idx & 63;
    float acc = nb[i];
    for (int t = 0; t < DKc; ++t) acc += na[i * DKc + t] * b[h * DKc + t];
    out[idx] = acc;
}

// Pack int32 mask -> bitmask (bit=1 keep).
__global__ __launch_bounds__(256) void pack_mask(const int* __restrict__ m,
                                                 unsigned* __restrict__ out) {
    size_t gid = (size_t)blockIdx.x * 256 + threadIdx.x;
    int v = m[gid];
    unsigned long long bal = __ballot(v != 0);
    int lane = threadIdx.x & 63;
    if (lane == 0)       out[gid >> 5] = (unsigned)bal;
    else if (lane == 32) out[gid >> 5] = (unsigned)(bal >> 32);
}

// ---------------------------------------------------------------------------
// Generic 128x128x(K) GEMM, C = A * B^T (+bias, epilogue variants).
// EPI 0: tanh(acc+bias[col]) [*log2e/(8*temp[h]) if temp] -> bf16 [B,H,S,DK]
// EPI 1: acc+bias[row] -> bf16 vT layout [B,H,DK,S], columns PERMUTED within
//        each 32-group so attn's PV can consume P directly from registers:
//        store col s at sp = (s&~31)|(((s>>2)&3)<<3)|(((s>>4)&1)<<2)|(s&3).
// EPI 2: acc+bias[col] -> fp32 merged [M,N]
// SWZ: XCD chunking. 1: each XCD owns contiguous y-panels (grids (8,64));
//      2: each XCD owns contiguous x-panels (grids (64,8)); 0: none.
template <bool AF32, bool BF32, int EPI, int SWZ>
__global__ __launch_bounds__(256) void gemm_k(const void* __restrict__ Ap,
                                              const void* __restrict__ Bp,
                                              const float* __restrict__ bias,
                                              void* __restrict__ outp,
                                              int Mdim, int Ndim, int Kdim,
                                              const float* __restrict__ temp) {
    constexpr int BK = 64;
    __shared__ unsigned char As[128 * 128];  // 128 rows x 128B (64 bf16)
    __shared__ unsigned char Bs[128 * 128];

    int bx = blockIdx.x, by = blockIdx.y;
    if constexpr (SWZ != 0) {
        int nwg = gridDim.x * gridDim.y;
        int L = by * gridDim.x + bx;
        int cpx = nwg >> 3;                       // blocks per XCD (nwg % 8 == 0)
        int orig = (L & 7) * cpx + (L >> 3);
        if constexpr (SWZ == 1) { bx = orig % gridDim.x; by = orig / gridDim.x; }
        else                    { by = orig % gridDim.y; bx = orig / gridDim.y; }
    }

    const int tid = threadIdx.x, lane = tid & 63, wave = tid >> 6;
    const int wr = wave >> 1, wc = wave & 1;
    const int m0 = by * 128, n0 = bx * 128;

    f32x4 acc[4][4] = {};

    const int nK = Kdim / BK;
    for (int kt = 0; kt < nK; ++kt) {
        const int k0 = kt * BK;
        float4 afr[8]; uint4 abr[4];
        float4 bfr[8]; uint4 bbr[4];
        if constexpr (AF32) {
            const float* A = (const float*)Ap;
            const int c4 = tid & 15;
#pragma unroll
            for (int i = 0; i < 8; ++i) {
                int row = (tid >> 4) + 16 * i;
                afr[i] = *(const float4*)(A + (size_t)(m0 + row) * Kdim + k0 + c4 * 4);
            }
        } else {
            const unsigned short* A = (const unsigned short*)Ap;
            const int c8 = tid & 7;
#pragma unroll
            for (int i = 0; i < 4; ++i) {
                int row = (tid >> 3) + 32 * i;
                abr[i] = *(const uint4*)(A + (size_t)(m0 + row) * Kdim + k0 + c8 * 8);
            }
        }
        if constexpr (BF32) {
            const float* Bm = (const float*)Bp;
            const int c4 = tid & 15;
#pragma unroll
            for (int i = 0; i < 8; ++i) {
                int row = (tid >> 4) + 16 * i;
                bfr[i] = *(const float4*)(Bm + (size_t)(n0 + row) * Kdim + k0 + c4 * 4);
            }
        } else {
            const unsigned short* Bm = (const unsigned short*)Bp;
            const int c8 = tid & 7;
#pragma unroll
            for (int i = 0; i < 4; ++i) {
                int row = (tid >> 3) + 32 * i;
                bbr[i] = *(const uint4*)(Bm + (size_t)(n0 + row) * Kdim + k0 + c8 * 8);
            }
        }
        __syncthreads();   // previous tile's LDS reads complete
        if constexpr (AF32) {
            const int colb = (tid & 15) * 8;
#pragma unroll
            for (int i = 0; i < 8; ++i) {
                int row = (tid >> 4) + 16 * i;
                uint2 u; u.x = pack2(afr[i].x, afr[i].y); u.y = pack2(afr[i].z, afr[i].w);
                *(uint2*)(As + row * 128 + (colb ^ ((row & 7) << 4))) = u;
            }
        } else {
            const int colb = (tid & 7) * 16;
#pragma unroll
            for (int i = 0; i < 4; ++i) {
                int row = (tid >> 3) + 32 * i;
                *(uint4*)(As + row * 128 + (colb ^ ((row & 7) << 4))) = abr[i];
            }
        }
        if constexpr (BF32) {
            const int colb = (tid & 15) * 8;
#pragma unroll
            for (int i = 0; i < 8; ++i) {
                int row = (tid >> 4) + 16 * i;
                uint2 u; u.x = pack2(bfr[i].x, bfr[i].y); u.y = pack2(bfr[i].z, bfr[i].w);
                *(uint2*)(Bs + row * 128 + (colb ^ ((row & 7) << 4))) = u;
            }
        } else {
            const int colb = (tid & 7) * 16;
#pragma unroll
            for (int i = 0; i < 4; ++i) {
                int row = (tid >> 3) + 32 * i;
                *(uint4*)(Bs + row * 128 + (colb ^ ((row & 7) << 4))) = bbr[i];
            }
        }
        __syncthreads();
#pragma unroll
        for (int s = 0; s < 2; ++s) {
            const int cb = s * 64 + (lane >> 4) * 16;
            bf16x8 a[4], b[4];
#pragma unroll
            for (int m = 0; m < 4; ++m) {
                int row = wr * 64 + m * 16 + (lane & 15);
                a[m] = *(const bf16x8*)(As + row * 128 + (cb ^ ((row & 7) << 4)));
            }
#pragma unroll
            for (int n = 0; n < 4; ++n) {
                int row = wc * 64 + n * 16 + (lane & 15);
                b[n] = *(const bf16x8*)(Bs + row * 128 + (cb ^ ((row & 7) << 4)));
            }
#pragma unroll
            for (int m = 0; m < 4; ++m)
#pragma unroll
                for (int n = 0; n < 4; ++n)
                    acc[m][n] = __builtin_amdgcn_mfma_f32_16x16x32_bf16(a[m], b[n], acc[m][n], 0, 0, 0);
        }
    }

    // Epilogue. C/D layout: row=(lane>>4)*4+r, col=lane&15.
#pragma unroll
    for (int m = 0; m < 4; ++m)
#pragma unroll
        for (int n = 0; n < 4; ++n) {
            int gn = n0 + wc * 64 + n * 16 + (lane & 15);
            float sc_h = 1.f;
            if constexpr (EPI == 0) {
                if (temp != nullptr) sc_h = 0.18033688011112042f * __builtin_amdgcn_rcpf(temp[gn >> 6]);
            }
#pragma unroll
            for (int r = 0; r < 4; ++r) {
                int gm = m0 + wr * 64 + m * 16 + ((lane >> 4) << 2) + r;
                float v = acc[m][n][r];
                if constexpr (EPI == 0) {
                    v = tanhf(v + bias[gn]) * sc_h;
                    int b = gm >> 11, s = gm & 2047, hh = gn >> 6, dk = gn & 63;
                    ((unsigned short*)outp)[(((size_t)(b * Hc + hh)) * Sc + s) * DKc + dk] = f2bf(v);
                } else if constexpr (EPI == 1) {
                    v += bias[gm];
                    int hh = gm >> 6, dk = gm & 63, b = gn >> 11, s = gn & 2047;
                    int sp = (s & ~31) | (((s >> 2) & 3) << 3) | (((s >> 4) & 1) << 2) | (s & 3);
                    ((unsigned short*)outp)[(((size_t)(b * Hc + hh)) * DKc + dk) * Sc + sp] = f2bf(v);
                } else {
                    v += bias[gn];
                    ((float*)outp)[(size_t)gm * Ndim + gn] = v;
                }
            }
        }
}

// ---------------------------------------------------------------------------
// Flash attention, zero-LDS, barrier-free. Grid 1024 (XCD-swizzled), 512 thr
// (8 independent waves, 16 q-rows each). K/V operand fragments batch-loaded
// into register arrays (8-16 loads in flight -> one L2 round trip per phase);
// V batches issue before softmax so VALU work hides their latency (T14).
// P never leaves registers: PV's k-axis is permuted (V columns pre-permuted
// in the vT GEMM epilogue) so each lane's sc[] IS the MFMA A-fragment.
__global__ __launch_bounds__(512) void attn_k(const ushort_t* __restrict__ qn,
                                              const ushort_t* __restrict__ kn,
                                              const ushort_t* __restrict__ vtp,
                                              const unsigned* __restrict__ mbits,
                                              ushort_t* __restrict__ ctxb) {
    const int tid = threadIdx.x, lane = tid & 63, wave = tid >> 6;
    const int q = lane & 15, g = lane >> 4;

    // bijective XCD swizzle: XCD x gets orig ids [x*128, x*128+128) = one b, 8 heads
    const int wg = blockIdx.x;
    const int orig = (wg & 7) * 128 + (wg >> 3);
    const int qt = orig & 15, h = (orig >> 4) & 15, b = orig >> 8;
    const int q0 = qt * 128;
    const int qrow = q0 + wave * 16 + q;
    const size_t headoff = ((size_t)(b * Hc + h)) * Sc * DKc;

    const ushort_t* Kbase = kn + headoff + (size_t)q * DKc + g * 8;
    const ushort_t* Vbase = vtp + headoff + (size_t)q * Sc + g * 8;

    bf16x8 qf0, qf1;
    {
        const ushort_t* p = qn + headoff + (size_t)qrow * DKc + g * 8;
        qf0 = *(const bf16x8*)p;
        qf1 = *(const bf16x8*)(p + 32);
    }
    const unsigned* mrow = mbits + ((size_t)b * Sc + qrow) * (Sc / 32);

    f32x4 ctxa[4] = {};
    float m_run = -1e30f, l_run = 0.f;

    for (int kt = 0; kt < Sc / 128; ++kt) {
        unsigned mw[4];
#pragma unroll
        for (int j = 0; j < 4; ++j) mw[j] = mrow[kt * 4 + j];

        // ---- K fragments: two register batches of 8 loads each
        const ushort_t* Kt = Kbase + (size_t)kt * 128 * DKc;
        bf16x8 ka[8], kb[8];
#pragma unroll
        for (int f = 0; f < 4; ++f) {
            ka[2 * f]     = *(const bf16x8*)(Kt + (size_t)f * 16 * DKc);
            ka[2 * f + 1] = *(const bf16x8*)(Kt + (size_t)f * 16 * DKc + 32);
        }
#pragma unroll
        for (int f = 0; f < 4; ++f) {
            kb[2 * f]     = *(const bf16x8*)(Kt + (size_t)(f + 4) * 16 * DKc);
            kb[2 * f + 1] = *(const bf16x8*)(Kt + (size_t)(f + 4) * 16 * DKc + 32);
        }

        f32x4 sc[8] = {};
        __builtin_amdgcn_s_setprio(1);
#pragma unroll
        for (int f = 0; f < 4; ++f) {
            sc[f] = __builtin_amdgcn_mfma_f32_16x16x32_bf16(ka[2 * f],     qf0, sc[f], 0, 0, 0);
            sc[f] = __builtin_amdgcn_mfma_f32_16x16x32_bf16(ka[2 * f + 1], qf1, sc[f], 0, 0, 0);
        }
#pragma unroll
        for (int f = 0; f < 4; ++f) {
            sc[4 + f] = __builtin_amdgcn_mfma_f32_16x16x32_bf16(kb[2 * f],     qf0, sc[4 + f], 0, 0, 0);
            sc[4 + f] = __builtin_amdgcn_mfma_f32_16x16x32_bf16(kb[2 * f + 1], qf1, sc[4 + f], 0, 0, 0);
        }
        __builtin_amdgcn_s_setprio(0);

        // ---- V batch A (cs=0,1): in flight during softmax
        const ushort_t* Vt = Vbase + kt * 128;
        bf16x8 va[8];
#pragma unroll
        for (int cs = 0; cs < 2; ++cs)
#pragma unroll
            for (int j = 0; j < 4; ++j)
                va[cs * 4 + j] = *(const bf16x8*)(Vt + (size_t)j * 16 * Sc + cs * 32);

        // ---- online softmax in base-2 (scores pre-scaled by log2e/(8*temp))
        float tmax = -1e30f;
#pragma unroll
        for (int f = 0; f < 8; ++f) {
            float m01 = fmaxf(sc[f][0], sc[f][1]);
            float m23 = fmaxf(sc[f][2], sc[f][3]);
            tmax = fmaxf(tmax, fmaxf(m01, m23));
        }
        tmax = fmaxf(tmax, __shfl_xor(tmax, 16));
        tmax = fmaxf(tmax, __shfl_xor(tmax, 32));
        if (!__all(tmax - m_run <= 12.f)) {          // defer-max (base-2 THR=12)
            float newm = fmaxf(m_run, tmax);
            float alpha = __builtin_amdgcn_exp2f(m_run - newm);
            l_run *= alpha;
            float al[4];
#pragma unroll
            for (int r = 0; r < 4; ++r) al[r] = __shfl(alpha, (g << 2) + r);
#pragma unroll
            for (int j = 0; j < 4; ++j)
#pragma unroll
                for (int r = 0; r < 4; ++r) ctxa[j][r] *= al[r];
            m_run = newm;
        }
        float tsum = 0.f;
#pragma unroll
        for (int f = 0; f < 8; ++f) {
            unsigned w = mw[f >> 1];
#pragma unroll
            for (int r = 0; r < 4; ++r) {
                int bit = ((f & 1) << 4) + (g << 2) + r;
                float e = __builtin_amdgcn_exp2f(sc[f][r] - m_run);
                e = ((w >> bit) & 1u) ? e : 0.f;
                sc[f][r] = e;
                tsum += e;
            }
        }
        tsum += __shfl_xor(tsum, 16);
        tsum += __shfl_xor(tsum, 32);
        l_run += tsum;

        // ---- V batch B (cs=2,3): in flight during first PV half
        bf16x8 vb[8];
#pragma unroll
        for (int cs = 0; cs < 2; ++cs)
#pragma unroll
            for (int j = 0; j < 4; ++j)
                vb[cs * 4 + j] = *(const bf16x8*)(Vt + (size_t)j * 16 * Sc + (cs + 2) * 32);

        // ---- PV: P comes straight from sc registers (k-permuted V)
        __builtin_amdgcn_s_setprio(1);
#pragma unroll
        for (int cs = 0; cs < 2; ++cs) {
            bf16x8 pa;
#pragma unroll
            for (int r = 0; r < 4; ++r) {
                pa[r]     = (__bf16)sc[2 * cs][r];
                pa[4 + r] = (__bf16)sc[2 * cs + 1][r];
            }
#pragma unroll
            for (int j = 0; j < 4; ++j)
                ctxa[j] = __builtin_amdgcn_mfma_f32_16x16x32_bf16(pa, va[cs * 4 + j], ctxa[j], 0, 0, 0);
        }
#pragma unroll
        for (int cs = 2; cs < 4; ++cs) {
            bf16x8 pa;
#pragma unroll
            for (int r = 0; r < 4; ++r) {
                pa[r]     = (__bf16)sc[2 * cs][r];
                pa[4 + r] = (__bf16)sc[2 * cs + 1][r];
            }
#pragma unroll
            for (int j = 0; j < 4; ++j)
                ctxa[j] = __builtin_amdgcn_mfma_f32_16x16x32_bf16(pa, vb[(cs - 2) * 4 + j], ctxa[j], 0, 0, 0);
        }
        __builtin_amdgcn_s_setprio(0);
    }

    // ---- epilogue: normalize by row-sum of accumulator's own q, write bf16 ctx
    float lv[4];
#pragma unroll
    for (int r = 0; r < 4; ++r) {
        float lr = __shfl(l_run, (g << 2) + r);
        lv[r] = __builtin_amdgcn_rcpf(lr);
    }
#pragma unroll
    for (int j = 0; j < 4; ++j)
#pragma unroll
        for (int r = 0; r < 4; ++r) {
            int srow = q0 + wave * 16 + (g << 2) + r;
            int col = h * DKc + j * 16 + q;
            float v = ctxa[j][r] * lv[r];
            ctxb[((size_t)b * Sc + srow) * Dc + col] = __builtin_bit_cast(unsigned short, (__bf16)v);
        }
}

// ---------------------------------------------------------------------------
__global__ __launch_bounds__(256) void rmsnorm_k(float* __restrict__ out,
                                                 const float* __restrict__ w) {
    const int row = blockIdx.x, tid = threadIdx.x;
    float4* p = (float4*)(out + (size_t)row * Dc) + tid;
    float4 v = *p;
    float ss = v.x * v.x + v.y * v.y + v.z * v.z + v.w * v.w;
#pragma unroll
    for (int o = 32; o >= 1; o >>= 1) ss += __shfl_xor(ss, o);
    __shared__ float sm[4];
    if ((tid & 63) == 0) sm[tid >> 6] = ss;
    __syncthreads();
    float tot = sm[0] + sm[1] + sm[2] + sm[3];
    float r = rsqrtf(tot * (1.f / Dc) + 1e-8f);
    float4 wv = *((const float4*)w + tid);
    v.x *= r * wv.x; v.y *= r * wv.y; v.z *= r * wv.z; v.w *= r * wv.w;
    *p = v;
}

// ---------------------------------------------------------------------------
extern "C" void kernel_launch(void* const* d_in, const int* in_sizes, int n_in,
                              void* d_out, int out_size, void* d_ws, size_t ws_size,
                              hipStream_t stream) {
    (void)in_sizes; (void)n_in; (void)out_size; (void)ws_size;
    const float* Q    = (const float*)d_in[0];
    const float* K    = (const float*)d_in[1];
    const float* V    = (const float*)d_in[2];
    const int*   mask = (const int*)  d_in[3];
    const float* wq   = (const float*)d_in[4];
    const float* bq   = (const float*)d_in[5];
    const float* wk   = (const float*)d_in[6];
    const float* bk   = (const float*)d_in[7];
    const float* wv   = (const float*)d_in[8];
    const float* bv   = (const float*)d_in[9];
    const float* wo   = (const float*)d_in[10];
    const float* bo   = (const float*)d_in[11];
    const float* naqw = (const float*)d_in[12];
    const float* naqb = (const float*)d_in[13];
    const float* nakw = (const float*)d_in[14];
    const float* nakb = (const float*)d_in[15];
    const float* temp = (const float*)d_in[16];
    const float* rmsw = (const float*)d_in[17];

    char* ws = (char*)d_ws;
    size_t off = 0;
    auto take = [&](size_t n) { char* p = ws + off; off += (n + 255) & ~(size_t)255; return p; };
    unsigned short* qnb  = (unsigned short*)take((size_t)Mc * Dc * 2);
    unsigned short* knb  = (unsigned short*)take((size_t)Mc * Dc * 2);
    unsigned short* vtb  = (unsigned short*)take((size_t)Mc * Dc * 2);
    unsigned short* ctxb = (unsigned short*)take((size_t)Mc * Dc * 2);
    unsigned short* wqf  = (unsigned short*)take((size_t)Dc * Dc * 2);
    unsigned short* wkf  = (unsigned short*)take((size_t)Dc * Dc * 2);
    unsigned short* wvf  = (unsigned short*)take((size_t)Dc * Dc * 2);
    unsigned short* wof  = (unsigned short*)take((size_t)Dc * Dc * 2);
    float*    bqf   = (float*)take(Dc * 4);
    float*    bkf   = (float*)take(Dc * 4);
    unsigned* mbits = (unsigned*)take((size_t)Bc * Sc * (Sc / 32) * 4);

    fold_w<<<dim3(Dc * Dc / 256), 256, 0, stream>>>(naqw, wq, wqf);
    fold_w<<<dim3(Dc * Dc / 256), 256, 0, stream>>>(nakw, wk, wkf);
    conv_w<<<dim3(Dc * Dc / 256), 256, 0, stream>>>(wv, wvf);
    conv_w<<<dim3(Dc * Dc / 256), 256, 0, stream>>>(wo, wof);
    fold_b<<<dim3((Dc + 255) / 256), 256, 0, stream>>>(naqw, bq, naqb, bqf);
    fold_b<<<dim3((Dc + 255) / 256), 256, 0, stream>>>(nakw, bk, nakb, bkf);
    pack_mask<<<dim3(Bc * Sc * Sc / 256), 256, 0, stream>>>(mask, mbits);

    // qn = tanh(Q @ Wq'^T + bq') * log2e/(8*temp[h]);  kn = tanh(K @ Wk'^T + bk')
    gemm_k<true, false, 0, 1><<<dim3(Dc / 128, Mc / 128), 256, 0, stream>>>(
        Q, wqf, bqf, qnb, Mc, Dc, Dc, temp);
    gemm_k<true, false, 0, 1><<<dim3(Dc / 128, Mc / 128), 256, 0, stream>>>(
        K, wkf, bkf, knb, Mc, Dc, Dc, nullptr);
    // v^T = Wv @ V_in^T + bv  (bf16, [B,H,DK,S], columns k-permuted for PV)
    gemm_k<false, true, 1, 2><<<dim3(Mc / 128, Dc / 128), 256, 0, stream>>>(
        wvf, V, bv, vtb, Dc, Mc, Dc, nullptr);

    attn_k<<<dim3(1024), 512, 0, stream>>>(qnb, knb, vtb, mbits, ctxb);

    // out = ctx @ wo^T + bo (fp32 into d_out), then in-place RMSNorm
    gemm_k<false, false, 2, 1><<<dim3(Dc / 128, Mc / 128), 256, 0, stream>>>(
        ctxb, wof, bo, d_out, Mc, Dc, Dc, nullptr);
    rmsnorm_k<<<dim3(Mc), 256, 0, stream>>>((float*)d_out, rmsw);
}

// Round 5
// 477.272 us; speedup vs baseline: 1.8375x; 1.7417x over previous
//
#include <hip/hip_runtime.h>
#include <hip/hip_bf16.h>

// Problem constants
constexpr int Bc  = 4;
constexpr int Sc  = 2048;
constexpr int Dc  = 1024;
constexpr int Hc  = 16;
constexpr int DKc = 64;
constexpr int Mc  = Bc * Sc;      // 8192 token rows

typedef __bf16 bf16x8 __attribute__((ext_vector_type(8)));
typedef float  f32x4  __attribute__((ext_vector_type(4)));
typedef unsigned short ushort_t;

#define DEV __device__ __forceinline__

DEV unsigned short f2bf(float f) {
    unsigned u = __builtin_bit_cast(unsigned, f);
    u += 0x7FFFu + ((u >> 16) & 1u);            // RNE
    return (unsigned short)(u >> 16);
}
DEV unsigned pack2(float a, float b) {
    return (unsigned)f2bf(a) | ((unsigned)f2bf(b) << 16);
}
// async global->LDS, 16B per lane; LDS dest = wave-uniform base + lane*16
DEV void gl16(const void* g, void* l) {
    __builtin_amdgcn_global_load_lds((const __attribute__((address_space(1))) unsigned int*)g,
                                     (__attribute__((address_space(3))) unsigned int*)l, 16, 0, 0);
}

// ---------------------------------------------------------------------------
__global__ __launch_bounds__(256) void fold_w(const float* __restrict__ na,
                                              const float* __restrict__ w,
                                              unsigned short* __restrict__ out) {
    int idx = blockIdx.x * 256 + threadIdx.x;   // 0 .. D*D-1
    int col = idx & (Dc - 1);
    int row = idx >> 10;
    int h = row >> 6, i = row & 63;
    float acc = 0.f;
#pragma unroll 8
    for (int t = 0; t < DKc; ++t)
        acc += na[i * DKc + t] * w[(h * DKc + t) * Dc + col];
    out[idx] = f2bf(acc);
}

__global__ __launch_bounds__(256) void conv_w(const float* __restrict__ w,
                                              unsigned short* __restrict__ out) {
    int i = blockIdx.x * 256 + threadIdx.x;
    out[i] = f2bf(w[i]);
}

__global__ __launch_bounds__(256) void fold_b(const float* __restrict__ na,
                                              const float* __restrict__ b,
                                              const float* __restrict__ nb,
                                              float* __restrict__ out) {
    int idx = blockIdx.x * 256 + threadIdx.x;
    if (idx >= Dc) return;
    int h = idx >> 6, i = idx & 63;
    float acc = nb[i];
    for (int t = 0; t < DKc; ++t) acc += na[i * DKc + t] * b[h * DKc + t];
    out[idx] = acc;
}

// Pack int32 mask -> bitmask (bit=1 keep).
__global__ __launch_bounds__(256) void pack_mask(const int* __restrict__ m,
                                                 unsigned* __restrict__ out) {
    size_t gid = (size_t)blockIdx.x * 256 + threadIdx.x;
    int v = m[gid];
    unsigned long long bal = __ballot(v != 0);
    int lane = threadIdx.x & 63;
    if (lane == 0)       out[gid >> 5] = (unsigned)bal;
    else if (lane == 32) out[gid >> 5] = (unsigned)(bal >> 32);
}

// ---------------------------------------------------------------------------
// Generic 128x128x(K) GEMM, C = A * B^T (+bias, epilogue variants).
// EPI 0: tanh(acc+bias[col]) [*log2e/(8*temp[h]) if temp] -> bf16 [B,H,S,DK]
// EPI 3: tanh(acc+bias[col]) -> kn TILE-SWIZZLED: [B,H][kt:16][row:128][64 elem]
//        with byte_in_row ^= (row&7)<<4  (ready for linear global_load_lds)
// EPI 1: acc+bias[row] -> vt TILE-SWIZZLED [B,H][kt:16][dk:64][128 elem]:
//        k permuted within 32-groups for in-reg P (sp), then byte ^= (dk&7)<<4
// EPI 2: acc+bias[col] -> fp32 merged [M,N]
// SWZ: XCD chunking (1: y-panels contiguous per XCD; 2: x-panels).
template <bool AF32, bool BF32, int EPI, int SWZ>
__global__ __launch_bounds__(256) void gemm_k(const void* __restrict__ Ap,
                                              const void* __restrict__ Bp,
                                              const float* __restrict__ bias,
                                              void* __restrict__ outp,
                                              int Mdim, int Ndim, int Kdim,
                                              const float* __restrict__ temp) {
    constexpr int BK = 64;
    __shared__ unsigned char As[128 * 128];  // 128 rows x 128B (64 bf16)
    __shared__ unsigned char Bs[128 * 128];

    int bx = blockIdx.x, by = blockIdx.y;
    if constexpr (SWZ != 0) {
        int nwg = gridDim.x * gridDim.y;
        int L = by * gridDim.x + bx;
        int cpx = nwg >> 3;                       // blocks per XCD (nwg % 8 == 0)
        int orig = (L & 7) * cpx + (L >> 3);
        if constexpr (SWZ == 1) { bx = orig % gridDim.x; by = orig / gridDim.x; }
        else                    { by = orig % gridDim.y; bx = orig / gridDim.y; }
    }

    const int tid = threadIdx.x, lane = tid & 63, wave = tid >> 6;
    const int wr = wave >> 1, wc = wave & 1;
    const int m0 = by * 128, n0 = bx * 128;

    f32x4 acc[4][4] = {};

    const int nK = Kdim / BK;
    for (int kt = 0; kt < nK; ++kt) {
        const int k0 = kt * BK;
        float4 afr[8]; uint4 abr[4];
        float4 bfr[8]; uint4 bbr[4];
        if constexpr (AF32) {
            const float* A = (const float*)Ap;
            const int c4 = tid & 15;
#pragma unroll
            for (int i = 0; i < 8; ++i) {
                int row = (tid >> 4) + 16 * i;
                afr[i] = *(const float4*)(A + (size_t)(m0 + row) * Kdim + k0 + c4 * 4);
            }
        } else {
            const unsigned short* A = (const unsigned short*)Ap;
            const int c8 = tid & 7;
#pragma unroll
            for (int i = 0; i < 4; ++i) {
                int row = (tid >> 3) + 32 * i;
                abr[i] = *(const uint4*)(A + (size_t)(m0 + row) * Kdim + k0 + c8 * 8);
            }
        }
        if constexpr (BF32) {
            const float* Bm = (const float*)Bp;
            const int c4 = tid & 15;
#pragma unroll
            for (int i = 0; i < 8; ++i) {
                int row = (tid >> 4) + 16 * i;
                bfr[i] = *(const float4*)(Bm + (size_t)(n0 + row) * Kdim + k0 + c4 * 4);
            }
        } else {
            const unsigned short* Bm = (const unsigned short*)Bp;
            const int c8 = tid & 7;
#pragma unroll
            for (int i = 0; i < 4; ++i) {
                int row = (tid >> 3) + 32 * i;
                bbr[i] = *(const uint4*)(Bm + (size_t)(n0 + row) * Kdim + k0 + c8 * 8);
            }
        }
        __syncthreads();   // previous tile's LDS reads complete
        if constexpr (AF32) {
            const int colb = (tid & 15) * 8;
#pragma unroll
            for (int i = 0; i < 8; ++i) {
                int row = (tid >> 4) + 16 * i;
                uint2 u; u.x = pack2(afr[i].x, afr[i].y); u.y = pack2(afr[i].z, afr[i].w);
                *(uint2*)(As + row * 128 + (colb ^ ((row & 7) << 4))) = u;
            }
        } else {
            const int colb = (tid & 7) * 16;
#pragma unroll
            for (int i = 0; i < 4; ++i) {
                int row = (tid >> 3) + 32 * i;
                *(uint4*)(As + row * 128 + (colb ^ ((row & 7) << 4))) = abr[i];
            }
        }
        if constexpr (BF32) {
            const int colb = (tid & 15) * 8;
#pragma unroll
            for (int i = 0; i < 8; ++i) {
                int row = (tid >> 4) + 16 * i;
                uint2 u; u.x = pack2(bfr[i].x, bfr[i].y); u.y = pack2(bfr[i].z, bfr[i].w);
                *(uint2*)(Bs + row * 128 + (colb ^ ((row & 7) << 4))) = u;
            }
        } else {
            const int colb = (tid & 7) * 16;
#pragma unroll
            for (int i = 0; i < 4; ++i) {
                int row = (tid >> 3) + 32 * i;
                *(uint4*)(Bs + row * 128 + (colb ^ ((row & 7) << 4))) = bbr[i];
            }
        }
        __syncthreads();
#pragma unroll
        for (int s = 0; s < 2; ++s) {
            const int cb = s * 64 + (lane >> 4) * 16;
            bf16x8 a[4], b[4];
#pragma unroll
            for (int m = 0; m < 4; ++m) {
                int row = wr * 64 + m * 16 + (lane & 15);
                a[m] = *(const bf16x8*)(As + row * 128 + (cb ^ ((row & 7) << 4)));
            }
#pragma unroll
            for (int n = 0; n < 4; ++n) {
                int row = wc * 64 + n * 16 + (lane & 15);
                b[n] = *(const bf16x8*)(Bs + row * 128 + (cb ^ ((row & 7) << 4)));
            }
#pragma unroll
            for (int m = 0; m < 4; ++m)
#pragma unroll
                for (int n = 0; n < 4; ++n)
                    acc[m][n] = __builtin_amdgcn_mfma_f32_16x16x32_bf16(a[m], b[n], acc[m][n], 0, 0, 0);
        }
    }

    // Epilogue. C/D layout: row=(lane>>4)*4+r, col=lane&15.
#pragma unroll
    for (int m = 0; m < 4; ++m)
#pragma unroll
        for (int n = 0; n < 4; ++n) {
            int gn = n0 + wc * 64 + n * 16 + (lane & 15);
            float sc_h = 1.f;
            if constexpr (EPI == 0) {
                if (temp != nullptr) sc_h = 0.18033688011112042f * __builtin_amdgcn_rcpf(temp[gn >> 6]);
            }
#pragma unroll
            for (int r = 0; r < 4; ++r) {
                int gm = m0 + wr * 64 + m * 16 + ((lane >> 4) << 2) + r;
                float v = acc[m][n][r];
                if constexpr (EPI == 0) {
                    v = tanhf(v + bias[gn]) * sc_h;
                    int b = gm >> 11, s = gm & 2047, hh = gn >> 6, dk = gn & 63;
                    ((unsigned short*)outp)[(((size_t)(b * Hc + hh)) * Sc + s) * DKc + dk] = f2bf(v);
                } else if constexpr (EPI == 3) {
                    v = tanhf(v + bias[gn]);
                    int b = gm >> 11, s = gm & 2047, hh = gn >> 6, dk = gn & 63;
                    int kt2 = s >> 7, row = s & 127;
                    int eofs = ((dk * 2) ^ ((row & 7) << 4)) >> 1;
                    size_t idx = ((size_t)(b * Hc + hh)) * Sc * DKc + (size_t)kt2 * 8192 + row * 64 + eofs;
                    ((unsigned short*)outp)[idx] = f2bf(v);
                } else if constexpr (EPI == 1) {
                    v += bias[gm];
                    int hh = gm >> 6, dk = gm & 63, b = gn >> 11, s = gn & 2047;
                    int sp = (s & ~31) | (((s >> 2) & 3) << 3) | (((s >> 4) & 1) << 2) | (s & 3);
                    int kt2 = sp >> 7, kloc = sp & 127;
                    int eofs = ((kloc * 2) ^ ((dk & 7) << 4)) >> 1;
                    size_t idx = ((size_t)(b * Hc + hh)) * Sc * DKc + (size_t)kt2 * 8192 + dk * 128 + eofs;
                    ((unsigned short*)outp)[idx] = f2bf(v);
                } else {
                    v += bias[gn];
                    ((float*)outp)[(size_t)gm * Ndim + gn] = v;
                }
            }
        }
}

// ---------------------------------------------------------------------------
// Flash attention with LDS double-buffered K/V staging via global_load_lds
// (T3-minimum 2-phase). Grid 1024 (XCD-swizzled), 512 thr = 8 waves, each
// owning 16 q-rows; all waves share the staged K/V tiles. Producers write
// K/V pre-swizzled (tile layout + XOR) so staging is a linear 16 KB copy.
// P never leaves registers (k-permuted V); softmax in base-2 with defer-max.
__global__ __launch_bounds__(512) void attn_k(const ushort_t* __restrict__ qn,
                                              const ushort_t* __restrict__ kn,
                                              const ushort_t* __restrict__ vtp,
                                              const unsigned* __restrict__ mbits,
                                              ushort_t* __restrict__ ctxb) {
    __shared__ __align__(16) unsigned char Kl[2][16384];   // [kt&1][row:128][128B swz]
    __shared__ __align__(16) unsigned char Vl[2][16384];   // [kt&1][dk:64][256B swz]

    const int tid = threadIdx.x, lane = tid & 63, wave = tid >> 6;
    const int q = lane & 15, g = lane >> 4;

    // bijective XCD swizzle: XCD x gets orig ids [x*128, x*128+128)
    const int wg = blockIdx.x;
    const int orig = (wg & 7) * 128 + (wg >> 3);
    const int qt = orig & 15, h = (orig >> 4) & 15, b = orig >> 8;
    const int q0 = qt * 128;
    const int qrow = q0 + wave * 16 + q;
    const size_t headoff = ((size_t)(b * Hc + h)) * Sc * DKc;

    const unsigned char* Ksrc = (const unsigned char*)(kn + headoff);
    const unsigned char* Vsrc = (const unsigned char*)(vtp + headoff);
    const int so = wave * 1024 + lane * 16;        // staging source offset
    const int ld = wave * 1024;                    // staging LDS base (wave-uniform)

    bf16x8 qf0, qf1;
    {
        const ushort_t* p = qn + headoff + (size_t)qrow * DKc + g * 8;
        qf0 = *(const bf16x8*)p;
        qf1 = *(const bf16x8*)(p + 32);
    }
    const unsigned* mrow = mbits + ((size_t)b * Sc + qrow) * (Sc / 32);

    // prologue: stage tile 0 into buffer 0
    gl16(Ksrc + so,        &Kl[0][ld]);
    gl16(Ksrc + 8192 + so, &Kl[0][8192 + ld]);
    gl16(Vsrc + so,        &Vl[0][ld]);
    gl16(Vsrc + 8192 + so, &Vl[0][8192 + ld]);

    f32x4 ctxa[4] = {};
    float m_run = -1e30f, l_run = 0.f;
    const int swz = (q & 7) << 4;
    __syncthreads();

    for (int kt = 0; kt < Sc / 128; ++kt) {
        const int cur = kt & 1;
        // ---- stage next tile into the other buffer (async, zero VGPR)
        if (kt < Sc / 128 - 1) {
            const unsigned char* ks = Ksrc + (kt + 1) * 16384;
            const unsigned char* vs = Vsrc + (kt + 1) * 16384;
            gl16(ks + so,        &Kl[cur ^ 1][ld]);
            gl16(ks + 8192 + so, &Kl[cur ^ 1][8192 + ld]);
            gl16(vs + so,        &Vl[cur ^ 1][ld]);
            gl16(vs + 8192 + so, &Vl[cur ^ 1][8192 + ld]);
        }
        unsigned mw[4];
#pragma unroll
        for (int j = 0; j < 4; ++j) mw[j] = mrow[kt * 4 + j];

        // ---- QK^T from LDS K tile
        f32x4 sc[8] = {};
        const unsigned char* Kb = Kl[cur];
        __builtin_amdgcn_s_setprio(1);
#pragma unroll
        for (int f = 0; f < 8; ++f) {
            const int ro = (f * 16 + q) * 128;
            bf16x8 a0 = *(const bf16x8*)(Kb + ro + ((g * 16) ^ swz));
            bf16x8 a1 = *(const bf16x8*)(Kb + ro + ((64 + g * 16) ^ swz));
            sc[f] = __builtin_amdgcn_mfma_f32_16x16x32_bf16(a0, qf0, sc[f], 0, 0, 0);
            sc[f] = __builtin_amdgcn_mfma_f32_16x16x32_bf16(a1, qf1, sc[f], 0, 0, 0);
        }
        __builtin_amdgcn_s_setprio(0);

        // ---- online softmax in base-2 (scores pre-scaled by log2e/(8*temp))
        float tmax = -1e30f;
#pragma unroll
        for (int f = 0; f < 8; ++f) {
            float m01 = fmaxf(sc[f][0], sc[f][1]);
            float m23 = fmaxf(sc[f][2], sc[f][3]);
            tmax = fmaxf(tmax, fmaxf(m01, m23));
        }
        tmax = fmaxf(tmax, __shfl_xor(tmax, 16));
        tmax = fmaxf(tmax, __shfl_xor(tmax, 32));
        if (!__all(tmax - m_run <= 12.f)) {          // defer-max (base-2 THR=12)
            float newm = fmaxf(m_run, tmax);
            float alpha = __builtin_amdgcn_exp2f(m_run - newm);
            l_run *= alpha;
            float al[4];
#pragma unroll
            for (int r = 0; r < 4; ++r) al[r] = __shfl(alpha, (g << 2) + r);
#pragma unroll
            for (int j = 0; j < 4; ++j)
#pragma unroll
                for (int r = 0; r < 4; ++r) ctxa[j][r] *= al[r];
            m_run = newm;
        }
        float tsum = 0.f;
#pragma unroll
        for (int f = 0; f < 8; ++f) {
            unsigned w = mw[f >> 1];
#pragma unroll
            for (int r = 0; r < 4; ++r) {
                int bit = ((f & 1) << 4) + (g << 2) + r;
                float e = __builtin_amdgcn_exp2f(sc[f][r] - m_run);
                e = ((w >> bit) & 1u) ? e : 0.f;
                sc[f][r] = e;
                tsum += e;
            }
        }
        tsum += __shfl_xor(tsum, 16);
        tsum += __shfl_xor(tsum, 32);
        l_run += tsum;

        // ---- PV from LDS V tile; P straight from sc registers (k-permuted V)
        const unsigned char* Vb = Vl[cur];
        __builtin_amdgcn_s_setprio(1);
#pragma unroll
        for (int cs = 0; cs < 4; ++cs) {
            bf16x8 pa;
#pragma unroll
            for (int r = 0; r < 4; ++r) {
                pa[r]     = (__bf16)sc[2 * cs][r];
                pa[4 + r] = (__bf16)sc[2 * cs + 1][r];
            }
#pragma unroll
            for (int j = 0; j < 4; ++j) {
                bf16x8 vb = *(const bf16x8*)(Vb + (j * 16 + q) * 256 + ((cs * 64 + g * 16) ^ swz));
                ctxa[j] = __builtin_amdgcn_mfma_f32_16x16x32_bf16(pa, vb, ctxa[j], 0, 0, 0);
            }
        }
        __builtin_amdgcn_s_setprio(0);

        __syncthreads();   // staged kt+1 complete (vmcnt) + all waves done with cur
    }

    // ---- epilogue: normalize by row-sum of accumulator's own q, write bf16 ctx
    float lv[4];
#pragma unroll
    for (int r = 0; r < 4; ++r) {
        float lr = __shfl(l_run, (g << 2) + r);
        lv[r] = __builtin_amdgcn_rcpf(lr);
    }
#pragma unroll
    for (int j = 0; j < 4; ++j)
#pragma unroll
        for (int r = 0; r < 4; ++r) {
            int srow = q0 + wave * 16 + (g << 2) + r;
            int col = h * DKc + j * 16 + q;
            float v = ctxa[j][r] * lv[r];
            ctxb[((size_t)b * Sc + srow) * Dc + col] = __builtin_bit_cast(unsigned short, (__bf16)v);
        }
}

// ---------------------------------------------------------------------------
__global__ __launch_bounds__(256) void rmsnorm_k(float* __restrict__ out,
                                                 const float* __restrict__ w) {
    const int row = blockIdx.x, tid = threadIdx.x;
    float4* p = (float4*)(out + (size_t)row * Dc) + tid;
    float4 v = *p;
    float ss = v.x * v.x + v.y * v.y + v.z * v.z + v.w * v.w;
#pragma unroll
    for (int o = 32; o >= 1; o >>= 1) ss += __shfl_xor(ss, o);
    __shared__ float sm[4];
    if ((tid & 63) == 0) sm[tid >> 6] = ss;
    __syncthreads();
    float tot = sm[0] + sm[1] + sm[2] + sm[3];
    float r = rsqrtf(tot * (1.f / Dc) + 1e-8f);
    float4 wv = *((const float4*)w + tid);
    v.x *= r * wv.x; v.y *= r * wv.y; v.z *= r * wv.z; v.w *= r * wv.w;
    *p = v;
}

// ---------------------------------------------------------------------------
extern "C" void kernel_launch(void* const* d_in, const int* in_sizes, int n_in,
                              void* d_out, int out_size, void* d_ws, size_t ws_size,
                              hipStream_t stream) {
    (void)in_sizes; (void)n_in; (void)out_size; (void)ws_size;
    const float* Q    = (const float*)d_in[0];
    const float* K    = (const float*)d_in[1];
    const float* V    = (const float*)d_in[2];
    const int*   mask = (const int*)  d_in[3];
    const float* wq   = (const float*)d_in[4];
    const float* bq   = (const float*)d_in[5];
    const float* wk   = (const float*)d_in[6];
    const float* bk   = (const float*)d_in[7];
    const float* wv   = (const float*)d_in[8];
    const float* bv   = (const float*)d_in[9];
    const float* wo   = (const float*)d_in[10];
    const float* bo   = (const float*)d_in[11];
    const float* naqw = (const float*)d_in[12];
    const float* naqb = (const float*)d_in[13];
    const float* nakw = (const float*)d_in[14];
    const float* nakb = (const float*)d_in[15];
    const float* temp = (const float*)d_in[16];
    const float* rmsw = (const float*)d_in[17];

    char* ws = (char*)d_ws;
    size_t off = 0;
    auto take = [&](size_t n) { char* p = ws + off; off += (n + 255) & ~(size_t)255; return p; };
    unsigned short* qnb  = (unsigned short*)take((size_t)Mc * Dc * 2);
    unsigned short* knb  = (unsigned short*)take((size_t)Mc * Dc * 2);
    unsigned short* vtb  = (unsigned short*)take((size_t)Mc * Dc * 2);
    unsigned short* ctxb = (unsigned short*)take((size_t)Mc * Dc * 2);
    unsigned short* wqf  = (unsigned short*)take((size_t)Dc * Dc * 2);
    unsigned short* wkf  = (unsigned short*)take((size_t)Dc * Dc * 2);
    unsigned short* wvf  = (unsigned short*)take((size_t)Dc * Dc * 2);
    unsigned short* wof  = (unsigned short*)take((size_t)Dc * Dc * 2);
    float*    bqf   = (float*)take(Dc * 4);
    float*    bkf   = (float*)take(Dc * 4);
    unsigned* mbits = (unsigned*)take((size_t)Bc * Sc * (Sc / 32) * 4);

    fold_w<<<dim3(Dc * Dc / 256), 256, 0, stream>>>(naqw, wq, wqf);
    fold_w<<<dim3(Dc * Dc / 256), 256, 0, stream>>>(nakw, wk, wkf);
    conv_w<<<dim3(Dc * Dc / 256), 256, 0, stream>>>(wv, wvf);
    conv_w<<<dim3(Dc * Dc / 256), 256, 0, stream>>>(wo, wof);
    fold_b<<<dim3((Dc + 255) / 256), 256, 0, stream>>>(naqw, bq, naqb, bqf);
    fold_b<<<dim3((Dc + 255) / 256), 256, 0, stream>>>(nakw, bk, nakb, bkf);
    pack_mask<<<dim3(Bc * Sc * Sc / 256), 256, 0, stream>>>(mask, mbits);

    // qn = tanh(Q @ Wq'^T + bq') * log2e/(8*temp[h])   (normal head layout)
    gemm_k<true, false, 0, 1><<<dim3(Dc / 128, Mc / 128), 256, 0, stream>>>(
        Q, wqf, bqf, qnb, Mc, Dc, Dc, temp);
    // kn = tanh(K @ Wk'^T + bk')   (tile-swizzled for linear LDS staging)
    gemm_k<true, false, 3, 1><<<dim3(Dc / 128, Mc / 128), 256, 0, stream>>>(
        K, wkf, bkf, knb, Mc, Dc, Dc, nullptr);
    // v^T = Wv @ V_in^T + bv   (tile-swizzled + k-permuted for in-reg P)
    gemm_k<false, true, 1, 2><<<dim3(Mc / 128, Dc / 128), 256, 0, stream>>>(
        wvf, V, bv, vtb, Dc, Mc, Dc, nullptr);

    attn_k<<<dim3(1024), 512, 0, stream>>>(qnb, knb, vtb, mbits, ctxb);

    // out = ctx @ wo^T + bo (fp32 into d_out), then in-place RMSNorm
    gemm_k<false, false, 2, 1><<<dim3(Dc / 128, Mc / 128), 256, 0, stream>>>(
        ctxb, wof, bo, d_out, Mc, Dc, Dc, nullptr);
    rmsnorm_k<<<dim3(Mc), 256, 0, stream>>>((float*)d_out, rmsw);
}

// Round 6
// 445.506 us; speedup vs baseline: 1.9686x; 1.0713x over previous
//
#include <hip/hip_runtime.h>
#include <hip/hip_bf16.h>

// Problem constants
constexpr int Bc  = 4;
constexpr int Sc  = 2048;
constexpr int Dc  = 1024;
constexpr int Hc  = 16;
constexpr int DKc = 64;
constexpr int Mc  = Bc * Sc;      // 8192 token rows

typedef __bf16 bf16x8 __attribute__((ext_vector_type(8)));
typedef float  f32x4  __attribute__((ext_vector_type(4)));
typedef unsigned short ushort_t;

#define DEV __device__ __forceinline__

DEV unsigned short f2bf(float f) {
    unsigned u = __builtin_bit_cast(unsigned, f);
    u += 0x7FFFu + ((u >> 16) & 1u);            // RNE
    return (unsigned short)(u >> 16);
}
DEV unsigned pack2(float a, float b) {
    return (unsigned)f2bf(a) | ((unsigned)f2bf(b) << 16);
}
// async global->LDS, 16B per lane; LDS dest = wave-uniform base + lane*16
DEV void gl16(const void* g, void* l) {
    __builtin_amdgcn_global_load_lds((const __attribute__((address_space(1))) unsigned int*)g,
                                     (__attribute__((address_space(3))) unsigned int*)l, 16, 0, 0);
}
DEV f32x4 mfma16(bf16x8 a, bf16x8 b, f32x4 c) {
    return __builtin_amdgcn_mfma_f32_16x16x32_bf16(a, b, c, 0, 0, 0);
}

// k-permutation bookkeeping (kn rows + mask bits stored permuted so that
// attn's in-register P fragments line up with NATURAL-order V):
//   stored p holds natural n = pi(p);  pi(p) = p4<<5 | p3:2<<3 | p5<<2 | p1:0
//   pi_inv(n) = n5<<4 | n4:3<<2 | n2<<5 | n1:0     (within 64-groups)

// ---------------------------------------------------------------------------
// Weight prep: z=0: wqf=fold(naqw,wq); z=1: wkf=fold(nakw,wk); z=2/3: bf16 conv
__global__ __launch_bounds__(256) void prep_w(const float* __restrict__ naqw,
                                              const float* __restrict__ wq,
                                              unsigned short* __restrict__ wqf,
                                              const float* __restrict__ nakw,
                                              const float* __restrict__ wk,
                                              unsigned short* __restrict__ wkf,
                                              const float* __restrict__ wv,
                                              unsigned short* __restrict__ wvf,
                                              const float* __restrict__ wo,
                                              unsigned short* __restrict__ wof) {
    const int z = blockIdx.z;
    const int idx = blockIdx.x * 256 + threadIdx.x;
    if (z >= 2) {
        const float* src = (z == 2) ? wv : wo;
        unsigned short* dst = (z == 2) ? wvf : wof;
        dst[idx] = f2bf(src[idx]);
        return;
    }
    const float* na = (z == 0) ? naqw : nakw;
    const float* w  = (z == 0) ? wq : wk;
    unsigned short* dst = (z == 0) ? wqf : wkf;
    int col = idx & (Dc - 1);
    int row = idx >> 10;
    int h = row >> 6, i = row & 63;
    float acc = 0.f;
#pragma unroll 8
    for (int t = 0; t < DKc; ++t)
        acc += na[i * DKc + t] * w[(h * DKc + t) * Dc + col];
    dst[idx] = f2bf(acc);
}

// z=0: bqf = naqw@bq + naqb ; z=1: bkf = nakw@bk + nakb
__global__ __launch_bounds__(256) void fold_b(const float* __restrict__ naqw,
                                              const float* __restrict__ bq,
                                              const float* __restrict__ naqb,
                                              float* __restrict__ bqf,
                                              const float* __restrict__ nakw,
                                              const float* __restrict__ bk,
                                              const float* __restrict__ nakb,
                                              float* __restrict__ bkf) {
    const int z = blockIdx.z;
    const float* na = z ? nakw : naqw;
    const float* b  = z ? bk : bq;
    const float* nb = z ? nakb : naqb;
    float* out      = z ? bkf : bqf;
    int idx = blockIdx.x * 256 + threadIdx.x;
    if (idx >= Dc) return;
    int h = idx >> 6, i = idx & 63;
    float acc = nb[i];
    for (int t = 0; t < DKc; ++t) acc += na[i * DKc + t] * b[h * DKc + t];
    out[idx] = acc;
}

// Pack int32 mask -> bitmask in PI-PERMUTED k order (matches kn row storage):
// stored bit position p within its 64-group holds mask[natural pi(p)].
__global__ __launch_bounds__(256) void pack_mask(const int* __restrict__ m,
                                                 unsigned* __restrict__ out) {
    size_t gid = (size_t)blockIdx.x * 256 + threadIdx.x;
    int p = threadIdx.x & 63;
    int nat = (((p >> 4) & 1) << 5) | (((p >> 2) & 3) << 3) | (((p >> 5) & 1) << 2) | (p & 3);
    int v = m[(gid & ~(size_t)63) | nat];
    unsigned long long bal = __ballot(v != 0);
    int lane = threadIdx.x & 63;
    if (lane == 0)       out[gid >> 5] = (unsigned)bal;
    else if (lane == 32) out[gid >> 5] = (unsigned)(bal >> 32);
}

// ---------------------------------------------------------------------------
// Generic 128x128x(K) GEMM, C = A * B^T (+bias, epilogue variants).
// EPI 0: tanh(acc+bias[col]) * log2e/(8*temp[h]) -> bf16 qn [B,H,S,DK]
// EPI 3: tanh(acc+bias[col]) -> kn tile layout [B,H][kt:16][prow:128][64]:
//        prow = pi_inv(natural row within tile), bytes XOR (prow&7)<<4
// EPI 1: acc+bias[row] -> vt tile layout [B,H][kt:16][dk:64][128] (natural k),
//        bytes XOR (dk&7)<<4
// EPI 2: acc+bias[col] -> fp32 merged [M,N]
// SWZ: XCD chunking (1: y-panels contiguous per XCD; 2: x-panels).
template <bool AF32, bool BF32, int EPI, int SWZ>
__global__ __launch_bounds__(256) void gemm_k(const void* __restrict__ Ap,
                                              const void* __restrict__ Bp,
                                              const float* __restrict__ bias,
                                              void* __restrict__ outp,
                                              int Mdim, int Ndim, int Kdim,
                                              const float* __restrict__ temp) {
    constexpr int BK = 64;
    __shared__ unsigned char As[128 * 128];  // 128 rows x 128B (64 bf16)
    __shared__ unsigned char Bs[128 * 128];

    int bx = blockIdx.x, by = blockIdx.y;
    if constexpr (SWZ != 0) {
        int nwg = gridDim.x * gridDim.y;
        int L = by * gridDim.x + bx;
        int cpx = nwg >> 3;                       // blocks per XCD (nwg % 8 == 0)
        int orig = (L & 7) * cpx + (L >> 3);
        if constexpr (SWZ == 1) { bx = orig % gridDim.x; by = orig / gridDim.x; }
        else                    { by = orig % gridDim.y; bx = orig / gridDim.y; }
    }

    const int tid = threadIdx.x, lane = tid & 63, wave = tid >> 6;
    const int wr = wave >> 1, wc = wave & 1;
    const int m0 = by * 128, n0 = bx * 128;

    f32x4 acc[4][4] = {};

    const int nK = Kdim / BK;
    for (int kt = 0; kt < nK; ++kt) {
        const int k0 = kt * BK;
        float4 afr[8]; uint4 abr[4];
        float4 bfr[8]; uint4 bbr[4];
        if constexpr (AF32) {
            const float* A = (const float*)Ap;
            const int c4 = tid & 15;
#pragma unroll
            for (int i = 0; i < 8; ++i) {
                int row = (tid >> 4) + 16 * i;
                afr[i] = *(const float4*)(A + (size_t)(m0 + row) * Kdim + k0 + c4 * 4);
            }
        } else {
            const unsigned short* A = (const unsigned short*)Ap;
            const int c8 = tid & 7;
#pragma unroll
            for (int i = 0; i < 4; ++i) {
                int row = (tid >> 3) + 32 * i;
                abr[i] = *(const uint4*)(A + (size_t)(m0 + row) * Kdim + k0 + c8 * 8);
            }
        }
        if constexpr (BF32) {
            const float* Bm = (const float*)Bp;
            const int c4 = tid & 15;
#pragma unroll
            for (int i = 0; i < 8; ++i) {
                int row = (tid >> 4) + 16 * i;
                bfr[i] = *(const float4*)(Bm + (size_t)(n0 + row) * Kdim + k0 + c4 * 4);
            }
        } else {
            const unsigned short* Bm = (const unsigned short*)Bp;
            const int c8 = tid & 7;
#pragma unroll
            for (int i = 0; i < 4; ++i) {
                int row = (tid >> 3) + 32 * i;
                bbr[i] = *(const uint4*)(Bm + (size_t)(n0 + row) * Kdim + k0 + c8 * 8);
            }
        }
        __syncthreads();   // previous tile's LDS reads complete
        if constexpr (AF32) {
            const int colb = (tid & 15) * 8;
#pragma unroll
            for (int i = 0; i < 8; ++i) {
                int row = (tid >> 4) + 16 * i;
                uint2 u; u.x = pack2(afr[i].x, afr[i].y); u.y = pack2(afr[i].z, afr[i].w);
                *(uint2*)(As + row * 128 + (colb ^ ((row & 7) << 4))) = u;
            }
        } else {
            const int colb = (tid & 7) * 16;
#pragma unroll
            for (int i = 0; i < 4; ++i) {
                int row = (tid >> 3) + 32 * i;
                *(uint4*)(As + row * 128 + (colb ^ ((row & 7) << 4))) = abr[i];
            }
        }
        if constexpr (BF32) {
            const int colb = (tid & 15) * 8;
#pragma unroll
            for (int i = 0; i < 8; ++i) {
                int row = (tid >> 4) + 16 * i;
                uint2 u; u.x = pack2(bfr[i].x, bfr[i].y); u.y = pack2(bfr[i].z, bfr[i].w);
                *(uint2*)(Bs + row * 128 + (colb ^ ((row & 7) << 4))) = u;
            }
        } else {
            const int colb = (tid & 7) * 16;
#pragma unroll
            for (int i = 0; i < 4; ++i) {
                int row = (tid >> 3) + 32 * i;
                *(uint4*)(Bs + row * 128 + (colb ^ ((row & 7) << 4))) = bbr[i];
            }
        }
        __syncthreads();
#pragma unroll
        for (int s = 0; s < 2; ++s) {
            const int cb = s * 64 + (lane >> 4) * 16;
            bf16x8 a[4], b[4];
#pragma unroll
            for (int m = 0; m < 4; ++m) {
                int row = wr * 64 + m * 16 + (lane & 15);
                a[m] = *(const bf16x8*)(As + row * 128 + (cb ^ ((row & 7) << 4)));
            }
#pragma unroll
            for (int n = 0; n < 4; ++n) {
                int row = wc * 64 + n * 16 + (lane & 15);
                b[n] = *(const bf16x8*)(Bs + row * 128 + (cb ^ ((row & 7) << 4)));
            }
#pragma unroll
            for (int m = 0; m < 4; ++m)
#pragma unroll
                for (int n = 0; n < 4; ++n)
                    acc[m][n] = mfma16(a[m], b[n], acc[m][n]);
        }
    }

    // Epilogue. C/D layout: row=(lane>>4)*4+r, col=lane&15.
#pragma unroll
    for (int m = 0; m < 4; ++m)
#pragma unroll
        for (int n = 0; n < 4; ++n) {
            int gn = n0 + wc * 64 + n * 16 + (lane & 15);
            float sc_h = 1.f;
            if constexpr (EPI == 0) {
                sc_h = 0.18033688011112042f * __builtin_amdgcn_rcpf(temp[gn >> 6]);
            }
#pragma unroll
            for (int r = 0; r < 4; ++r) {
                int gm = m0 + wr * 64 + m * 16 + ((lane >> 4) << 2) + r;
                float v = acc[m][n][r];
                if constexpr (EPI == 0) {
                    v = tanhf(v + bias[gn]) * sc_h;
                    int b = gm >> 11, s = gm & 2047, hh = gn >> 6, dk = gn & 63;
                    ((unsigned short*)outp)[(((size_t)(b * Hc + hh)) * Sc + s) * DKc + dk] = f2bf(v);
                } else if constexpr (EPI == 3) {
                    v = tanhf(v + bias[gn]);
                    int b = gm >> 11, s = gm & 2047, hh = gn >> 6, dk = gn & 63;
                    int kt2 = s >> 7, nr = s & 127;
                    int prow = (nr & 64) | (((nr >> 5) & 1) << 4) | (((nr >> 3) & 3) << 2)
                             | (((nr >> 2) & 1) << 5) | (nr & 3);
                    int eofs = ((dk * 2) ^ ((prow & 7) << 4)) >> 1;
                    size_t idx = ((size_t)(b * Hc + hh)) * Sc * DKc + (size_t)kt2 * 8192 + prow * 64 + eofs;
                    ((unsigned short*)outp)[idx] = f2bf(v);
                } else if constexpr (EPI == 1) {
                    v += bias[gm];
                    int hh = gm >> 6, dk = gm & 63, b = gn >> 11, s = gn & 2047;
                    int kt2 = s >> 7, kloc = s & 127;
                    int eofs = ((kloc * 2) ^ ((dk & 7) << 4)) >> 1;
                    size_t idx = ((size_t)(b * Hc + hh)) * Sc * DKc + (size_t)kt2 * 8192 + dk * 128 + eofs;
                    ((unsigned short*)outp)[idx] = f2bf(v);
                } else {
                    v += bias[gn];
                    ((float*)outp)[(size_t)gm * Ndim + gn] = v;
                }
            }
        }
}

// ---------------------------------------------------------------------------
// Flash attention. Grid 512 (XCD-swizzled), 512 thr = 8 waves x 32 q-rows
// (block = 256 q of one (b,h)). K/V LDS double-buffered via global_load_lds.
// NO-MAX softmax: scores tanh-bounded (|s|<=11.54 base-2 at temp=1) -> plain
// exp2, masking via cndmask to -1e30. Row-sum l computed by an extra MFMA
// against a ones-vector (lands in accumulator layout; zero shuffles).
// Each K/V fragment read feeds BOTH q-groups -> LDS traffic halved.
__global__ __launch_bounds__(512, 2) void attn_k(const ushort_t* __restrict__ qn,
                                                 const ushort_t* __restrict__ kn,
                                                 const ushort_t* __restrict__ vtp,
                                                 const unsigned* __restrict__ mbits,
                                                 ushort_t* __restrict__ ctxb) {
    __shared__ __align__(16) unsigned char Kl[2][16384];   // [buf][prow:128][128B swz]
    __shared__ __align__(16) unsigned char Vl[2][16384];   // [buf][dk:64][256B swz]

    const int tid = threadIdx.x, lane = tid & 63, wave = tid >> 6;
    const int q = lane & 15, g = lane >> 4;

    // bijective XCD swizzle: XCD x owns orig in [x*64, x*64+64) = one b, 8 heads
    const int wg = blockIdx.x;
    const int orig = (wg & 7) * 64 + (wg >> 3);
    const int qt = orig & 7, h = (orig >> 3) & 15, b = orig >> 7;
    const int q0 = qt * 256;
    const int qr0 = q0 + wave * 32 + q;
    const size_t headoff = ((size_t)(b * Hc + h)) * Sc * DKc;

    const unsigned char* Ksrc = (const unsigned char*)(kn + headoff);
    const unsigned char* Vsrc = (const unsigned char*)(vtp + headoff);
    const int so = wave * 1024 + lane * 16;        // staging source offset
    const int ld = wave * 1024;                    // staging LDS base (wave-uniform)

    bf16x8 qf[2][2];
    {
        const ushort_t* p0 = qn + headoff + (size_t)qr0 * DKc + g * 8;
        qf[0][0] = *(const bf16x8*)p0;
        qf[0][1] = *(const bf16x8*)(p0 + 32);
        qf[1][0] = *(const bf16x8*)(p0 + 16 * DKc);
        qf[1][1] = *(const bf16x8*)(p0 + 16 * DKc + 32);
    }
    const unsigned* mr0 = mbits + ((size_t)b * Sc + qr0) * (Sc / 32);
    const unsigned* mr1 = mr0 + 16 * (Sc / 32);

    bf16x8 ones;
#pragma unroll
    for (int i = 0; i < 8; ++i) ones[i] = (__bf16)1.0f;

    f32x4 ctxa[2][4] = {};
    f32x4 lacc[2] = {};
    const int swz = (q & 7) << 4;
    const int sh = g << 2;

    // prologue: stage tile 0 into buffer 0
    gl16(Ksrc + so,        &Kl[0][ld]);
    gl16(Ksrc + 8192 + so, &Kl[0][8192 + ld]);
    gl16(Vsrc + so,        &Vl[0][ld]);
    gl16(Vsrc + 8192 + so, &Vl[0][8192 + ld]);
    __syncthreads();

    for (int kt = 0; kt < Sc / 128; ++kt) {
        const int cur = kt & 1;
        if (kt < Sc / 128 - 1) {
            const unsigned char* ks = Ksrc + (kt + 1) * 16384;
            const unsigned char* vs = Vsrc + (kt + 1) * 16384;
            gl16(ks + so,        &Kl[cur ^ 1][ld]);
            gl16(ks + 8192 + so, &Kl[cur ^ 1][8192 + ld]);
            gl16(vs + so,        &Vl[cur ^ 1][ld]);
            gl16(vs + 8192 + so, &Vl[cur ^ 1][8192 + ld]);
        }
        unsigned mwq[2][4];
        {
            uint4 t0 = *(const uint4*)(mr0 + kt * 4);
            uint4 t1 = *(const uint4*)(mr1 + kt * 4);
            mwq[0][0] = t0.x >> sh; mwq[0][1] = t0.y >> sh;
            mwq[0][2] = t0.z >> sh; mwq[0][3] = t0.w >> sh;
            mwq[1][0] = t1.x >> sh; mwq[1][1] = t1.y >> sh;
            mwq[1][2] = t1.z >> sh; mwq[1][3] = t1.w >> sh;
        }
        const unsigned char* Kb = Kl[cur];
        const unsigned char* Vb = Vl[cur];

#pragma unroll
        for (int kh = 0; kh < 2; ++kh) {
            // ---- QK^T: 64 k-rows x 32 q; K-frags shared by both q-groups
            f32x4 s0[4] = {}, s1[4] = {};
            __builtin_amdgcn_s_setprio(1);
#pragma unroll
            for (int f = 0; f < 4; ++f) {
                const int ro = (kh * 64 + f * 16 + q) * 128;
                bf16x8 a0 = *(const bf16x8*)(Kb + ro + ((g * 16) ^ swz));
                bf16x8 a1 = *(const bf16x8*)(Kb + ro + ((64 + g * 16) ^ swz));
                s0[f] = mfma16(a0, qf[0][0], s0[f]);
                s0[f] = mfma16(a1, qf[0][1], s0[f]);
                s1[f] = mfma16(a0, qf[1][0], s1[f]);
                s1[f] = mfma16(a1, qf[1][1], s1[f]);
            }
            __builtin_amdgcn_s_setprio(0);

            // ---- mask + exp2 (no max tracking; pre-shifted mask words)
#pragma unroll
            for (int f = 0; f < 4; ++f) {
                unsigned w0 = mwq[0][kh * 2 + (f >> 1)];
                unsigned w1 = mwq[1][kh * 2 + (f >> 1)];
#pragma unroll
                for (int r = 0; r < 4; ++r) {
                    const unsigned bitc = 1u << (((f & 1) << 4) + r);
                    float v0 = (w0 & bitc) ? s0[f][r] : -1e30f;
                    float v1 = (w1 & bitc) ? s1[f][r] : -1e30f;
                    s0[f][r] = __builtin_amdgcn_exp2f(v0);
                    s1[f][r] = __builtin_amdgcn_exp2f(v1);
                }
            }

            // ---- pack P fragments (pi permutation makes sc k-order match V)
            bf16x8 pa0[2], pa1[2];
#pragma unroll
            for (int cs = 0; cs < 2; ++cs)
#pragma unroll
                for (int r = 0; r < 4; ++r) {
                    pa0[cs][r]     = (__bf16)s0[cs][r];
                    pa0[cs][4 + r] = (__bf16)s0[cs + 2][r];
                    pa1[cs][r]     = (__bf16)s1[cs][r];
                    pa1[cs][4 + r] = (__bf16)s1[cs + 2][r];
                }

            // ---- PV + l (ones-MFMA); V-frags shared by both q-groups
            __builtin_amdgcn_s_setprio(1);
#pragma unroll
            for (int cs = 0; cs < 2; ++cs) {
                const int csg = kh * 2 + cs;
                lacc[0] = mfma16(pa0[cs], ones, lacc[0]);
                lacc[1] = mfma16(pa1[cs], ones, lacc[1]);
#pragma unroll
                for (int j = 0; j < 4; ++j) {
                    bf16x8 vb = *(const bf16x8*)(Vb + (j * 16 + q) * 256 + ((csg * 64 + g * 16) ^ swz));
                    ctxa[0][j] = mfma16(pa0[cs], vb, ctxa[0][j]);
                    ctxa[1][j] = mfma16(pa1[cs], vb, ctxa[1][j]);
                }
            }
            __builtin_amdgcn_s_setprio(0);
        }
        __syncthreads();   // staged kt+1 complete + all waves done with cur
    }

    // ---- epilogue: normalize rows by l (already in accumulator layout)
#pragma unroll
    for (int qg = 0; qg < 2; ++qg) {
        f32x4 linv;
#pragma unroll
        for (int r = 0; r < 4; ++r) linv[r] = __builtin_amdgcn_rcpf(lacc[qg][r]);
#pragma unroll
        for (int j = 0; j < 4; ++j)
#pragma unroll
            for (int r = 0; r < 4; ++r) {
                int srow = q0 + wave * 32 + qg * 16 + (g << 2) + r;
                int col = h * DKc + j * 16 + q;
                float v = ctxa[qg][j][r] * linv[r];
                ctxb[((size_t)b * Sc + srow) * Dc + col] = __builtin_bit_cast(unsigned short, (__bf16)v);
            }
    }
}

// ---------------------------------------------------------------------------
__global__ __launch_bounds__(256) void rmsnorm_k(float* __restrict__ out,
                                                 const float* __restrict__ w) {
    const int row = blockIdx.x, tid = threadIdx.x;
    float4* p = (float4*)(out + (size_t)row * Dc) + tid;
    float4 v = *p;
    float ss = v.x * v.x + v.y * v.y + v.z * v.z + v.w * v.w;
#pragma unroll
    for (int o = 32; o >= 1; o >>= 1) ss += __shfl_xor(ss, o);
    __shared__ float sm[4];
    if ((tid & 63) == 0) sm[tid >> 6] = ss;
    __syncthreads();
    float tot = sm[0] + sm[1] + sm[2] + sm[3];
    float r = rsqrtf(tot * (1.f / Dc) + 1e-8f);
    float4 wv = *((const float4*)w + tid);
    v.x *= r * wv.x; v.y *= r * wv.y; v.z *= r * wv.z; v.w *= r * wv.w;
    *p = v;
}

// ---------------------------------------------------------------------------
extern "C" void kernel_launch(void* const* d_in, const int* in_sizes, int n_in,
                              void* d_out, int out_size, void* d_ws, size_t ws_size,
                              hipStream_t stream) {
    (void)in_sizes; (void)n_in; (void)out_size; (void)ws_size;
    const float* Q    = (const float*)d_in[0];
    const float* K    = (const float*)d_in[1];
    const float* V    = (const float*)d_in[2];
    const int*   mask = (const int*)  d_in[3];
    const float* wq   = (const float*)d_in[4];
    const float* bq   = (const float*)d_in[5];
    const float* wk   = (const float*)d_in[6];
    const float* bk   = (const float*)d_in[7];
    const float* wv   = (const float*)d_in[8];
    const float* bv   = (const float*)d_in[9];
    const float* wo   = (const float*)d_in[10];
    const float* bo   = (const float*)d_in[11];
    const float* naqw = (const float*)d_in[12];
    const float* naqb = (const float*)d_in[13];
    const float* nakw = (const float*)d_in[14];
    const float* nakb = (const float*)d_in[15];
    const float* temp = (const float*)d_in[16];
    const float* rmsw = (const float*)d_in[17];

    char* ws = (char*)d_ws;
    size_t off = 0;
    auto take = [&](size_t n) { char* p = ws + off; off += (n + 255) & ~(size_t)255; return p; };
    unsigned short* qnb  = (unsigned short*)take((size_t)Mc * Dc * 2);
    unsigned short* knb  = (unsigned short*)take((size_t)Mc * Dc * 2);
    unsigned short* vtb  = (unsigned short*)take((size_t)Mc * Dc * 2);
    unsigned short* ctxb = (unsigned short*)take((size_t)Mc * Dc * 2);
    unsigned short* wqf  = (unsigned short*)take((size_t)Dc * Dc * 2);
    unsigned short* wkf  = (unsigned short*)take((size_t)Dc * Dc * 2);
    unsigned short* wvf  = (unsigned short*)take((size_t)Dc * Dc * 2);
    unsigned short* wof  = (unsigned short*)take((size_t)Dc * Dc * 2);
    float*    bqf   = (float*)take(Dc * 4);
    float*    bkf   = (float*)take(Dc * 4);
    unsigned* mbits = (unsigned*)take((size_t)Bc * Sc * (Sc / 32) * 4);

    prep_w<<<dim3(Dc * Dc / 256, 1, 4), 256, 0, stream>>>(naqw, wq, wqf, nakw, wk, wkf,
                                                          wv, wvf, wo, wof);
    fold_b<<<dim3(4, 1, 2), 256, 0, stream>>>(naqw, bq, naqb, bqf, nakw, bk, nakb, bkf);
    pack_mask<<<dim3(Bc * Sc * Sc / 256), 256, 0, stream>>>(mask, mbits);

    // qn = tanh(Q @ Wq'^T + bq') * log2e/(8*temp[h])   (natural head layout)
    gemm_k<true, false, 0, 1><<<dim3(Dc / 128, Mc / 128), 256, 0, stream>>>(
        Q, wqf, bqf, qnb, Mc, Dc, Dc, temp);
    // kn = tanh(K @ Wk'^T + bk')   (tile layout, pi-permuted rows, XOR-swizzled)
    gemm_k<true, false, 3, 1><<<dim3(Dc / 128, Mc / 128), 256, 0, stream>>>(
        K, wkf, bkf, knb, Mc, Dc, Dc, nullptr);
    // v^T = Wv @ V_in^T + bv   (tile layout, natural k, XOR-swizzled)
    gemm_k<false, true, 1, 2><<<dim3(Mc / 128, Dc / 128), 256, 0, stream>>>(
        wvf, V, bv, vtb, Dc, Mc, Dc, nullptr);

    attn_k<<<dim3(512), 512, 0, stream>>>(qnb, knb, vtb, mbits, ctxb);

    // out = ctx @ wo^T + bo (fp32 into d_out), then in-place RMSNorm
    gemm_k<false, false, 2, 1><<<dim3(Dc / 128, Mc / 128), 256, 0, stream>>>(
        ctxb, wof, bo, d_out, Mc, Dc, Dc, nullptr);
    rmsnorm_k<<<dim3(Mc), 256, 0, stream>>>((float*)d_out, rmsw);
}

// Round 7
// 323.426 us; speedup vs baseline: 2.7116x; 1.3775x over previous
//
#include <hip/hip_runtime.h>
#include <hip/hip_bf16.h>

// Problem constants
constexpr int Bc  = 4;
constexpr int Sc  = 2048;
constexpr int Dc  = 1024;
constexpr int Hc  = 16;
constexpr int DKc = 64;
constexpr int Mc  = Bc * Sc;      // 8192 token rows

typedef __bf16 bf16x8 __attribute__((ext_vector_type(8)));
typedef float  f32x4  __attribute__((ext_vector_type(4)));
typedef unsigned short ushort_t;

#define DEV __device__ __forceinline__

DEV unsigned short f2bf(float f) {
    unsigned u = __builtin_bit_cast(unsigned, f);
    u += 0x7FFFu + ((u >> 16) & 1u);            // RNE
    return (unsigned short)(u >> 16);
}
DEV unsigned pack2(float a, float b) {
    return (unsigned)f2bf(a) | ((unsigned)f2bf(b) << 16);
}
// async global->LDS, 16B per lane; LDS dest = wave-uniform base + lane*16
DEV void gl16(const void* g, void* l) {
    __builtin_amdgcn_global_load_lds((const __attribute__((address_space(1))) unsigned int*)g,
                                     (__attribute__((address_space(3))) unsigned int*)l, 16, 0, 0);
}
DEV f32x4 mfma16(bf16x8 a, bf16x8 b, f32x4 c) {
    return __builtin_amdgcn_mfma_f32_16x16x32_bf16(a, b, c, 0, 0, 0);
}

// k-permutation bookkeeping (kn rows + mask bits stored permuted so that
// attn's in-register P fragments line up with NATURAL-order V):
//   stored p holds natural n = pi(p);  pi(p) = p4<<5 | p3:2<<3 | p5<<2 | p1:0

// ---------------------------------------------------------------------------
// fold_w2: wXf[h*64+i][col] = sum_t na[i][t] * w[h*64+t][col], w read ONCE.
// grid (4 colgroups, 16 h, 2 z), 256 threads (one col each).
__global__ __launch_bounds__(256) void fold_w2(const float* __restrict__ naqw,
                                               const float* __restrict__ wq,
                                               unsigned short* __restrict__ wqf,
                                               const float* __restrict__ nakw,
                                               const float* __restrict__ wk,
                                               unsigned short* __restrict__ wkf) {
    const int colg = blockIdx.x, h = blockIdx.y, z = blockIdx.z;
    const float* na = z ? nakw : naqw;
    const float* w  = z ? wk : wq;
    unsigned short* out = z ? wkf : wqf;
    const int col = colg * 256 + threadIdx.x;

    __shared__ float nal[64 * 64];
    for (int i = threadIdx.x; i < 4096; i += 256) nal[i] = na[i];

    float wr[64];
#pragma unroll
    for (int t = 0; t < 64; ++t) wr[t] = w[(h * 64 + t) * Dc + col];
    __syncthreads();

    for (int i = 0; i < 64; ++i) {
        float acc = 0.f;
#pragma unroll
        for (int t = 0; t < 64; ++t) acc += nal[i * 64 + t] * wr[t];
        out[(h * 64 + i) * Dc + col] = f2bf(acc);
    }
}

// bf16 conversion of wv / wo. grid (4096,1,2)
__global__ __launch_bounds__(256) void conv_w2(const float* __restrict__ wv,
                                               unsigned short* __restrict__ wvf,
                                               const float* __restrict__ wo,
                                               unsigned short* __restrict__ wof) {
    const int z = blockIdx.z;
    const int i = blockIdx.x * 256 + threadIdx.x;
    const float* s = z ? wo : wv;
    unsigned short* d = z ? wof : wvf;
    d[i] = f2bf(s[i]);
}

// Q,K fp32 -> bf16 (8 elems/thread). grid 8192.
__global__ __launch_bounds__(256) void conv_in(const float* __restrict__ Q,
                                               const float* __restrict__ K,
                                               ushort_t* __restrict__ qb,
                                               ushort_t* __restrict__ kb) {
    size_t i = ((size_t)blockIdx.x * 256 + threadIdx.x) * 8;
    constexpr size_t N = (size_t)Mc * Dc;
    const float* src = (i < N) ? Q + i : K + (i - N);
    ushort_t* dst    = (i < N) ? qb + i : kb + (i - N);
    float4 a = *(const float4*)src, b = *(const float4*)(src + 4);
    uint4 o;
    o.x = pack2(a.x, a.y); o.y = pack2(a.z, a.w);
    o.z = pack2(b.x, b.y); o.w = pack2(b.z, b.w);
    *(uint4*)dst = o;
}

// z=0: bqf = naqw@bq + naqb ; z=1: bkf = nakw@bk + nakb
__global__ __launch_bounds__(256) void fold_b(const float* __restrict__ naqw,
                                              const float* __restrict__ bq,
                                              const float* __restrict__ naqb,
                                              float* __restrict__ bqf,
                                              const float* __restrict__ nakw,
                                              const float* __restrict__ bk,
                                              const float* __restrict__ nakb,
                                              float* __restrict__ bkf) {
    const int z = blockIdx.z;
    const float* na = z ? nakw : naqw;
    const float* b  = z ? bk : bq;
    const float* nb = z ? nakb : naqb;
    float* out      = z ? bkf : bqf;
    int idx = blockIdx.x * 256 + threadIdx.x;
    if (idx >= Dc) return;
    int h = idx >> 6, i = idx & 63;
    float acc = nb[i];
    for (int t = 0; t < DKc; ++t) acc += na[i * DKc + t] * b[h * DKc + t];
    out[idx] = acc;
}

// Pack int32 mask -> bitmask in PI-PERMUTED k order (matches kn row storage).
__global__ __launch_bounds__(256) void pack_mask(const int* __restrict__ m,
                                                 unsigned* __restrict__ out) {
    size_t gid = (size_t)blockIdx.x * 256 + threadIdx.x;
    int p = threadIdx.x & 63;
    int nat = (((p >> 4) & 1) << 5) | (((p >> 2) & 3) << 3) | (((p >> 5) & 1) << 2) | (p & 3);
    int v = m[(gid & ~(size_t)63) | nat];
    unsigned long long bal = __ballot(v != 0);
    int lane = threadIdx.x & 63;
    if (lane == 0)       out[gid >> 5] = (unsigned)bal;
    else if (lane == 32) out[gid >> 5] = (unsigned)(bal >> 32);
}

// ---------------------------------------------------------------------------
// gemm_bt: C = A * B^T, m97 structure — 128x128 tile, BK=64, 4 waves,
// global_load_lds width-16 staging into LINEAR LDS, stage/sync/compute/sync.
// A always bf16 [Mdim,Kdim]. B bf16 unless BF32 (then fp32, reg-pack staged).
// EPI 0: tanh(acc+bias[col]) * log2e/(8*temp[h]) -> bf16 qn [B,H,S,DK]
// EPI 3: tanh(acc+bias[col]) -> kn tiles [B,H][kt:16][prow:128][64], pi+XOR
// EPI 1: acc+bias[row] -> vt tiles [B,H][kt:16][dk:64][128], XOR
// EPI 2: acc+bias[col] -> fp32 merged [M,N]
// SWZ: XCD chunking (1: y-panels contiguous per XCD; 2: x-panels).
template <int EPI, int SWZ, bool BF32>
__global__ __launch_bounds__(256) void gemm_bt(const ushort_t* __restrict__ A,
                                               const void* __restrict__ Bp,
                                               const float* __restrict__ bias,
                                               void* __restrict__ outp,
                                               int Mdim, int Ndim, int Kdim,
                                               const float* __restrict__ temp) {
    __shared__ __align__(16) unsigned char As[16384];   // [row:128][128B]
    __shared__ __align__(16) unsigned char Bs[16384];

    int bx = blockIdx.x, by = blockIdx.y;
    if constexpr (SWZ != 0) {
        int nwg = gridDim.x * gridDim.y;
        int L = by * gridDim.x + bx;
        int cpx = nwg >> 3;
        int orig = (L & 7) * cpx + (L >> 3);
        if constexpr (SWZ == 1) { bx = orig % gridDim.x; by = orig / gridDim.x; }
        else                    { by = orig % gridDim.y; bx = orig / gridDim.y; }
    }

    const int tid = threadIdx.x, lane = tid & 63, wave = tid >> 6;
    const int wr = wave >> 1, wc = wave & 1;
    const int q = lane & 15, g = lane >> 4;
    const int m0 = by * 128, n0 = bx * 128;

    // staging geometry: instr i covers tile rows (wave*4+i)*8 + (lane>>3),
    // col elems (lane&7)*8 — LDS dest (wave*4+i)*1024 + lane*16 (linear).
    const int strow = lane >> 3, stcol = (lane & 7) * 8;
    const ushort_t* Ab = A + (size_t)(m0 + strow) * Kdim + stcol;
    const ushort_t* Bb16 = nullptr;
    if constexpr (!BF32) Bb16 = (const ushort_t*)Bp + (size_t)(n0 + strow) * Kdim + stcol;
    const int c4 = tid & 15, brow0 = tid >> 4;

    float4 bfr[8];
    if constexpr (BF32) {
        const float* Bm = (const float*)Bp;
#pragma unroll
        for (int i = 0; i < 8; ++i)
            bfr[i] = *(const float4*)(Bm + (size_t)(n0 + brow0 + 16 * i) * Kdim + c4 * 4);
    }

    f32x4 acc[4][4] = {};
    const int nK = Kdim >> 6;
    for (int kt = 0; kt < nK; ++kt) {
        const int k0 = kt << 6;
        if constexpr (!BF32) {
#pragma unroll
            for (int i = 0; i < 4; ++i) {
                const int ro = (wave * 4 + i) * 8;
                gl16(Ab + (size_t)ro * Kdim + k0, As + (wave * 4 + i) * 1024);
                gl16(Bb16 + (size_t)ro * Kdim + k0, Bs + (wave * 4 + i) * 1024);
            }
            __syncthreads();   // staged (vmcnt drained at barrier)
        } else {
            __syncthreads();   // all waves done computing kt-1
#pragma unroll
            for (int i = 0; i < 4; ++i) {
                const int ro = (wave * 4 + i) * 8;
                gl16(Ab + (size_t)ro * Kdim + k0, As + (wave * 4 + i) * 1024);
            }
#pragma unroll
            for (int i = 0; i < 8; ++i) {
                uint2 u; u.x = pack2(bfr[i].x, bfr[i].y); u.y = pack2(bfr[i].z, bfr[i].w);
                *(uint2*)(Bs + (brow0 + 16 * i) * 128 + c4 * 8) = u;
            }
            if (kt + 1 < nK) {
                const float* Bm = (const float*)Bp;
#pragma unroll
                for (int i = 0; i < 8; ++i)
                    bfr[i] = *(const float4*)(Bm + (size_t)(n0 + brow0 + 16 * i) * Kdim + k0 + 64 + c4 * 4);
            }
            __syncthreads();   // A staged + B written
        }

#pragma unroll
        for (int s = 0; s < 2; ++s) {
            const int cb = s * 64 + g * 16;
            bf16x8 a[4], b[4];
#pragma unroll
            for (int m = 0; m < 4; ++m)
                a[m] = *(const bf16x8*)(As + (wr * 64 + m * 16 + q) * 128 + cb);
#pragma unroll
            for (int n = 0; n < 4; ++n)
                b[n] = *(const bf16x8*)(Bs + (wc * 64 + n * 16 + q) * 128 + cb);
#pragma unroll
            for (int m = 0; m < 4; ++m)
#pragma unroll
                for (int n = 0; n < 4; ++n)
                    acc[m][n] = mfma16(a[m], b[n], acc[m][n]);
        }
        if constexpr (!BF32) __syncthreads();   // reads done before next stage
    }

    // Epilogue. C/D layout: row=(lane>>4)*4+r, col=lane&15.
#pragma unroll
    for (int m = 0; m < 4; ++m)
#pragma unroll
        for (int n = 0; n < 4; ++n) {
            int gn = n0 + wc * 64 + n * 16 + q;
            float sc_h = 1.f;
            if constexpr (EPI == 0) {
                sc_h = 0.18033688011112042f * __builtin_amdgcn_rcpf(temp[gn >> 6]);
            }
#pragma unroll
            for (int r = 0; r < 4; ++r) {
                int gm = m0 + wr * 64 + m * 16 + (g << 2) + r;
                float v = acc[m][n][r];
                if constexpr (EPI == 0) {
                    v = tanhf(v + bias[gn]) * sc_h;
                    int b = gm >> 11, s = gm & 2047, hh = gn >> 6, dk = gn & 63;
                    ((unsigned short*)outp)[(((size_t)(b * Hc + hh)) * Sc + s) * DKc + dk] = f2bf(v);
                } else if constexpr (EPI == 3) {
                    v = tanhf(v + bias[gn]);
                    int b = gm >> 11, s = gm & 2047, hh = gn >> 6, dk = gn & 63;
                    int kt2 = s >> 7, nr = s & 127;
                    int prow = (nr & 64) | (((nr >> 5) & 1) << 4) | (((nr >> 3) & 3) << 2)
                             | (((nr >> 2) & 1) << 5) | (nr & 3);
                    int eofs = ((dk * 2) ^ ((prow & 7) << 4)) >> 1;
                    size_t idx = ((size_t)(b * Hc + hh)) * Sc * DKc + (size_t)kt2 * 8192 + prow * 64 + eofs;
                    ((unsigned short*)outp)[idx] = f2bf(v);
                } else if constexpr (EPI == 1) {
                    v += bias[gm];
                    int hh = gm >> 6, dk = gm & 63, b = gn >> 11, s = gn & 2047;
                    int kt2 = s >> 7, kloc = s & 127;
                    int eofs = ((kloc * 2) ^ ((dk & 7) << 4)) >> 1;
                    size_t idx = ((size_t)(b * Hc + hh)) * Sc * DKc + (size_t)kt2 * 8192 + dk * 128 + eofs;
                    ((unsigned short*)outp)[idx] = f2bf(v);
                } else {
                    v += bias[gn];
                    ((float*)outp)[(size_t)gm * Ndim + gn] = v;
                }
            }
        }
}

// ---------------------------------------------------------------------------
// Flash attention (unchanged from round 6 — at issue saturation).
__global__ __launch_bounds__(512, 2) void attn_k(const ushort_t* __restrict__ qn,
                                                 const ushort_t* __restrict__ kn,
                                                 const ushort_t* __restrict__ vtp,
                                                 const unsigned* __restrict__ mbits,
                                                 ushort_t* __restrict__ ctxb) {
    __shared__ __align__(16) unsigned char Kl[2][16384];   // [buf][prow:128][128B swz]
    __shared__ __align__(16) unsigned char Vl[2][16384];   // [buf][dk:64][256B swz]

    const int tid = threadIdx.x, lane = tid & 63, wave = tid >> 6;
    const int q = lane & 15, g = lane >> 4;

    const int wg = blockIdx.x;
    const int orig = (wg & 7) * 64 + (wg >> 3);
    const int qt = orig & 7, h = (orig >> 3) & 15, b = orig >> 7;
    const int q0 = qt * 256;
    const int qr0 = q0 + wave * 32 + q;
    const size_t headoff = ((size_t)(b * Hc + h)) * Sc * DKc;

    const unsigned char* Ksrc = (const unsigned char*)(kn + headoff);
    const unsigned char* Vsrc = (const unsigned char*)(vtp + headoff);
    const int so = wave * 1024 + lane * 16;
    const int ld = wave * 1024;

    bf16x8 qf[2][2];
    {
        const ushort_t* p0 = qn + headoff + (size_t)qr0 * DKc + g * 8;
        qf[0][0] = *(const bf16x8*)p0;
        qf[0][1] = *(const bf16x8*)(p0 + 32);
        qf[1][0] = *(const bf16x8*)(p0 + 16 * DKc);
        qf[1][1] = *(const bf16x8*)(p0 + 16 * DKc + 32);
    }
    const unsigned* mr0 = mbits + ((size_t)b * Sc + qr0) * (Sc / 32);
    const unsigned* mr1 = mr0 + 16 * (Sc / 32);

    bf16x8 ones;
#pragma unroll
    for (int i = 0; i < 8; ++i) ones[i] = (__bf16)1.0f;

    f32x4 ctxa[2][4] = {};
    f32x4 lacc[2] = {};
    const int swz = (q & 7) << 4;
    const int sh = g << 2;

    gl16(Ksrc + so,        &Kl[0][ld]);
    gl16(Ksrc + 8192 + so, &Kl[0][8192 + ld]);
    gl16(Vsrc + so,        &Vl[0][ld]);
    gl16(Vsrc + 8192 + so, &Vl[0][8192 + ld]);
    __syncthreads();

    for (int kt = 0; kt < Sc / 128; ++kt) {
        const int cur = kt & 1;
        if (kt < Sc / 128 - 1) {
            const unsigned char* ks = Ksrc + (kt + 1) * 16384;
            const unsigned char* vs = Vsrc + (kt + 1) * 16384;
            gl16(ks + so,        &Kl[cur ^ 1][ld]);
            gl16(ks + 8192 + so, &Kl[cur ^ 1][8192 + ld]);
            gl16(vs + so,        &Vl[cur ^ 1][ld]);
            gl16(vs + 8192 + so, &Vl[cur ^ 1][8192 + ld]);
        }
        unsigned mwq[2][4];
        {
            uint4 t0 = *(const uint4*)(mr0 + kt * 4);
            uint4 t1 = *(const uint4*)(mr1 + kt * 4);
            mwq[0][0] = t0.x >> sh; mwq[0][1] = t0.y >> sh;
            mwq[0][2] = t0.z >> sh; mwq[0][3] = t0.w >> sh;
            mwq[1][0] = t1.x >> sh; mwq[1][1] = t1.y >> sh;
            mwq[1][2] = t1.z >> sh; mwq[1][3] = t1.w >> sh;
        }
        const unsigned char* Kb = Kl[cur];
        const unsigned char* Vb = Vl[cur];

#pragma unroll
        for (int kh = 0; kh < 2; ++kh) {
            f32x4 s0[4] = {}, s1[4] = {};
            __builtin_amdgcn_s_setprio(1);
#pragma unroll
            for (int f = 0; f < 4; ++f) {
                const int ro = (kh * 64 + f * 16 + q) * 128;
                bf16x8 a0 = *(const bf16x8*)(Kb + ro + ((g * 16) ^ swz));
                bf16x8 a1 = *(const bf16x8*)(Kb + ro + ((64 + g * 16) ^ swz));
                s0[f] = mfma16(a0, qf[0][0], s0[f]);
                s0[f] = mfma16(a1, qf[0][1], s0[f]);
                s1[f] = mfma16(a0, qf[1][0], s1[f]);
                s1[f] = mfma16(a1, qf[1][1], s1[f]);
            }
            __builtin_amdgcn_s_setprio(0);

#pragma unroll
            for (int f = 0; f < 4; ++f) {
                unsigned w0 = mwq[0][kh * 2 + (f >> 1)];
                unsigned w1 = mwq[1][kh * 2 + (f >> 1)];
#pragma unroll
                for (int r = 0; r < 4; ++r) {
                    const unsigned bitc = 1u << (((f & 1) << 4) + r);
                    float v0 = (w0 & bitc) ? s0[f][r] : -1e30f;
                    float v1 = (w1 & bitc) ? s1[f][r] : -1e30f;
                    s0[f][r] = __builtin_amdgcn_exp2f(v0);
                    s1[f][r] = __builtin_amdgcn_exp2f(v1);
                }
            }

            bf16x8 pa0[2], pa1[2];
#pragma unroll
            for (int cs = 0; cs < 2; ++cs)
#pragma unroll
                for (int r = 0; r < 4; ++r) {
                    pa0[cs][r]     = (__bf16)s0[cs][r];
                    pa0[cs][4 + r] = (__bf16)s0[cs + 2][r];
                    pa1[cs][r]     = (__bf16)s1[cs][r];
                    pa1[cs][4 + r] = (__bf16)s1[cs + 2][r];
                }

            __builtin_amdgcn_s_setprio(1);
#pragma unroll
            for (int cs = 0; cs < 2; ++cs) {
                const int csg = kh * 2 + cs;
                lacc[0] = mfma16(pa0[cs], ones, lacc[0]);
                lacc[1] = mfma16(pa1[cs], ones, lacc[1]);
#pragma unroll
                for (int j = 0; j < 4; ++j) {
                    bf16x8 vb = *(const bf16x8*)(Vb + (j * 16 + q) * 256 + ((csg * 64 + g * 16) ^ swz));
                    ctxa[0][j] = mfma16(pa0[cs], vb, ctxa[0][j]);
                    ctxa[1][j] = mfma16(pa1[cs], vb, ctxa[1][j]);
                }
            }
            __builtin_amdgcn_s_setprio(0);
        }
        __syncthreads();
    }

#pragma unroll
    for (int qg = 0; qg < 2; ++qg) {
        f32x4 linv;
#pragma unroll
        for (int r = 0; r < 4; ++r) linv[r] = __builtin_amdgcn_rcpf(lacc[qg][r]);
#pragma unroll
        for (int j = 0; j < 4; ++j)
#pragma unroll
            for (int r = 0; r < 4; ++r) {
                int srow = q0 + wave * 32 + qg * 16 + (g << 2) + r;
                int col = h * DKc + j * 16 + q;
                float v = ctxa[qg][j][r] * linv[r];
                ctxb[((size_t)b * Sc + srow) * Dc + col] = __builtin_bit_cast(unsigned short, (__bf16)v);
            }
    }
}

// ---------------------------------------------------------------------------
__global__ __launch_bounds__(256) void rmsnorm_k(float* __restrict__ out,
                                                 const float* __restrict__ w) {
    const int row = blockIdx.x, tid = threadIdx.x;
    float4* p = (float4*)(out + (size_t)row * Dc) + tid;
    float4 v = *p;
    float ss = v.x * v.x + v.y * v.y + v.z * v.z + v.w * v.w;
#pragma unroll
    for (int o = 32; o >= 1; o >>= 1) ss += __shfl_xor(ss, o);
    __shared__ float sm[4];
    if ((tid & 63) == 0) sm[tid >> 6] = ss;
    __syncthreads();
    float tot = sm[0] + sm[1] + sm[2] + sm[3];
    float r = rsqrtf(tot * (1.f / Dc) + 1e-8f);
    float4 wv = *((const float4*)w + tid);
    v.x *= r * wv.x; v.y *= r * wv.y; v.z *= r * wv.z; v.w *= r * wv.w;
    *p = v;
}

// ---------------------------------------------------------------------------
extern "C" void kernel_launch(void* const* d_in, const int* in_sizes, int n_in,
                              void* d_out, int out_size, void* d_ws, size_t ws_size,
                              hipStream_t stream) {
    (void)in_sizes; (void)n_in; (void)out_size; (void)ws_size;
    const float* Q    = (const float*)d_in[0];
    const float* K    = (const float*)d_in[1];
    const float* V    = (const float*)d_in[2];
    const int*   mask = (const int*)  d_in[3];
    const float* wq   = (const float*)d_in[4];
    const float* bq   = (const float*)d_in[5];
    const float* wk   = (const float*)d_in[6];
    const float* bk   = (const float*)d_in[7];
    const float* wv   = (const float*)d_in[8];
    const float* bv   = (const float*)d_in[9];
    const float* wo   = (const float*)d_in[10];
    const float* bo   = (const float*)d_in[11];
    const float* naqw = (const float*)d_in[12];
    const float* naqb = (const float*)d_in[13];
    const float* nakw = (const float*)d_in[14];
    const float* nakb = (const float*)d_in[15];
    const float* temp = (const float*)d_in[16];
    const float* rmsw = (const float*)d_in[17];

    char* ws = (char*)d_ws;
    size_t off = 0;
    auto take = [&](size_t n) { char* p = ws + off; off += (n + 255) & ~(size_t)255; return p; };
    unsigned short* qnb  = (unsigned short*)take((size_t)Mc * Dc * 2);
    unsigned short* vtb  = (unsigned short*)take((size_t)Mc * Dc * 2);
    unsigned short* qb   = (unsigned short*)take((size_t)Mc * Dc * 2);
    unsigned short* kb   = (unsigned short*)take((size_t)Mc * Dc * 2);
    unsigned short* wqf  = (unsigned short*)take((size_t)Dc * Dc * 2);
    unsigned short* wkf  = (unsigned short*)take((size_t)Dc * Dc * 2);
    unsigned short* wvf  = (unsigned short*)take((size_t)Dc * Dc * 2);
    unsigned short* wof  = (unsigned short*)take((size_t)Dc * Dc * 2);
    float*    bqf   = (float*)take(Dc * 4);
    float*    bkf   = (float*)take(Dc * 4);
    unsigned* mbits = (unsigned*)take((size_t)Bc * Sc * (Sc / 32) * 4);
    // aliases (live ranges disjoint): knb reuses qb; ctxb reuses kb
    unsigned short* knb  = qb;   // qb dead after qn GEMM; kn GEMM runs after
    unsigned short* ctxb = kb;   // kb dead after kn GEMM; attn runs after

    fold_w2<<<dim3(4, 16, 2), 256, 0, stream>>>(naqw, wq, wqf, nakw, wk, wkf);
    conv_w2<<<dim3(Dc * Dc / 256, 1, 2), 256, 0, stream>>>(wv, wvf, wo, wof);
    fold_b<<<dim3(4, 1, 2), 256, 0, stream>>>(naqw, bq, naqb, bqf, nakw, bk, nakb, bkf);
    pack_mask<<<dim3(Bc * Sc * Sc / 256), 256, 0, stream>>>(mask, mbits);
    conv_in<<<dim3(2 * Mc * Dc / 8 / 256), 256, 0, stream>>>(Q, K, qb, kb);

    // v^T = Wv @ V_in^T + bv  (tile layout for attn staging; B=V stays fp32)
    gemm_bt<1, 2, true><<<dim3(Mc / 128, Dc / 128), 256, 0, stream>>>(
        wvf, V, bv, vtb, Dc, Mc, Dc, nullptr);
    // qn = tanh(Qb @ Wq'^T + bq') * log2e/(8*temp[h])
    gemm_bt<0, 1, false><<<dim3(Dc / 128, Mc / 128), 256, 0, stream>>>(
        qb, wqf, bqf, qnb, Mc, Dc, Dc, temp);
    // kn = tanh(Kb @ Wk'^T + bk')  (tile layout, pi-permuted rows, XOR swz)
    gemm_bt<3, 1, false><<<dim3(Dc / 128, Mc / 128), 256, 0, stream>>>(
        kb, wkf, bkf, knb, Mc, Dc, Dc, nullptr);

    attn_k<<<dim3(512), 512, 0, stream>>>(qnb, knb, vtb, mbits, ctxb);

    // out = ctx @ wo^T + bo (fp32 into d_out), then in-place RMSNorm
    gemm_bt<2, 1, false><<<dim3(Dc / 128, Mc / 128), 256, 0, stream>>>(
        ctxb, wof, bo, d_out, Mc, Dc, Dc, nullptr);
    rmsnorm_k<<<dim3(Mc), 256, 0, stream>>>((float*)d_out, rmsw);
}

// Round 8
// 307.001 us; speedup vs baseline: 2.8567x; 1.0535x over previous
//
#include <hip/hip_runtime.h>
#include <hip/hip_bf16.h>

// Problem constants
constexpr int Bc  = 4;
constexpr int Sc  = 2048;
constexpr int Dc  = 1024;
constexpr int Hc  = 16;
constexpr int DKc = 64;
constexpr int Mc  = Bc * Sc;      // 8192 token rows

typedef __bf16 bf16x8 __attribute__((ext_vector_type(8)));
typedef float  f32x4  __attribute__((ext_vector_type(4)));
typedef unsigned short ushort_t;

#define DEV __device__ __forceinline__

DEV unsigned short f2bf(float f) {
    unsigned u = __builtin_bit_cast(unsigned, f);
    u += 0x7FFFu + ((u >> 16) & 1u);            // RNE
    return (unsigned short)(u >> 16);
}
DEV unsigned pack2(float a, float b) {
    return (unsigned)f2bf(a) | ((unsigned)f2bf(b) << 16);
}
// async global->LDS, 16B per lane; LDS dest = wave-uniform base + lane*16
DEV void gl16(const void* g, void* l) {
    __builtin_amdgcn_global_load_lds((const __attribute__((address_space(1))) unsigned int*)g,
                                     (__attribute__((address_space(3))) unsigned int*)l, 16, 0, 0);
}
DEV f32x4 mfma16(bf16x8 a, bf16x8 b, f32x4 c) {
    return __builtin_amdgcn_mfma_f32_16x16x32_bf16(a, b, c, 0, 0, 0);
}

// k-permutation bookkeeping (kn rows + mask bits stored permuted so that
// attn's in-register P fragments line up with NATURAL-order V):
//   stored p holds natural n = pi(p);  pi(p) = p4<<5 | p3:2<<3 | p5<<2 | p1:0

// ---------------------------------------------------------------------------
// fold_w2: z<2: wXf[h*64+i][col] = sum_t na[i][t]*w[h*64+t][col] (w read once)
//          z==2: bias folds (blockIdx.y in {0,1} selects q/k; rest idle)
__global__ __launch_bounds__(256) void fold_w2(const float* __restrict__ naqw,
                                               const float* __restrict__ wq,
                                               unsigned short* __restrict__ wqf,
                                               const float* __restrict__ nakw,
                                               const float* __restrict__ wk,
                                               unsigned short* __restrict__ wkf,
                                               const float* __restrict__ bq,
                                               const float* __restrict__ naqb,
                                               float* __restrict__ bqf,
                                               const float* __restrict__ bk,
                                               const float* __restrict__ nakb,
                                               float* __restrict__ bkf) {
    const int colg = blockIdx.x, h = blockIdx.y, z = blockIdx.z;
    if (z == 2) {
        if (h >= 2) return;
        const float* na = h ? nakw : naqw;
        const float* b  = h ? bk : bq;
        const float* nb = h ? nakb : naqb;
        float* out      = h ? bkf : bqf;
        int idx = colg * 256 + threadIdx.x;
        if (idx >= Dc) return;
        int hh = idx >> 6, i = idx & 63;
        float acc = nb[i];
        for (int t = 0; t < DKc; ++t) acc += na[i * DKc + t] * b[hh * DKc + t];
        out[idx] = acc;
        return;
    }
    const float* na = z ? nakw : naqw;
    const float* w  = z ? wk : wq;
    unsigned short* out = z ? wkf : wqf;
    const int col = colg * 256 + threadIdx.x;

    __shared__ float nal[64 * 64];
    for (int i = threadIdx.x; i < 4096; i += 256) nal[i] = na[i];

    float wr[64];
#pragma unroll
    for (int t = 0; t < 64; ++t) wr[t] = w[(h * 64 + t) * Dc + col];
    __syncthreads();

    for (int i = 0; i < 64; ++i) {
        float acc = 0.f;
#pragma unroll
        for (int t = 0; t < 64; ++t) acc += nal[i * 64 + t] * wr[t];
        out[(h * 64 + i) * Dc + col] = f2bf(acc);
    }
}

// Convert Q,K,V,wv,wo fp32 -> bf16, 8 elems/thread. All range boundaries are
// multiples of 2048 elems, so each block is uniform. Grid 12800.
__global__ __launch_bounds__(256) void conv_all(const float* __restrict__ Q,
                                                const float* __restrict__ K,
                                                const float* __restrict__ V,
                                                const float* __restrict__ wv,
                                                const float* __restrict__ wo,
                                                ushort_t* __restrict__ qb,
                                                ushort_t* __restrict__ kb,
                                                ushort_t* __restrict__ vb,
                                                ushort_t* __restrict__ wvf,
                                                ushort_t* __restrict__ wof) {
    size_t i = ((size_t)blockIdx.x * 256 + threadIdx.x) * 8;
    constexpr size_t N = (size_t)Mc * Dc;   // 8M
    constexpr size_t W = (size_t)Dc * Dc;   // 1M
    const float* src; ushort_t* dst; size_t off;
    if      (i < N)         { src = Q;  dst = qb;  off = i; }
    else if (i < 2 * N)     { src = K;  dst = kb;  off = i - N; }
    else if (i < 3 * N)     { src = V;  dst = vb;  off = i - 2 * N; }
    else if (i < 3 * N + W) { src = wv; dst = wvf; off = i - 3 * N; }
    else                    { src = wo; dst = wof; off = i - 3 * N - W; }
    float4 a = *(const float4*)(src + off), b = *(const float4*)(src + off + 4);
    uint4 o;
    o.x = pack2(a.x, a.y); o.y = pack2(a.z, a.w);
    o.z = pack2(b.x, b.y); o.w = pack2(b.z, b.w);
    *(uint4*)(dst + off) = o;
}

// Pack int32 mask -> bitmask in PI-PERMUTED k order (matches kn row storage).
__global__ __launch_bounds__(256) void pack_mask(const int* __restrict__ m,
                                                 unsigned* __restrict__ out) {
    size_t gid = (size_t)blockIdx.x * 256 + threadIdx.x;
    int p = threadIdx.x & 63;
    int nat = (((p >> 4) & 1) << 5) | (((p >> 2) & 3) << 3) | (((p >> 5) & 1) << 2) | (p & 3);
    int v = m[(gid & ~(size_t)63) | nat];
    unsigned long long bal = __ballot(v != 0);
    int lane = threadIdx.x & 63;
    if (lane == 0)       out[gid >> 5] = (unsigned)bal;
    else if (lane == 32) out[gid >> 5] = (unsigned)(bal >> 32);
}

// ---------------------------------------------------------------------------
// gemm_bt: C = A * B^T, all-bf16, 128x128 tile, BK=64, 4 waves,
// global_load_lds width-16 staging, 2-phase LDS DOUBLE BUFFER:
//   stage(kt+1, buf^1)  ->  compute(buf)  ->  one __syncthreads per K-step.
// EPI 0: tanh(acc+bias[col]) * log2e/(8*temp[h]) -> bf16 qn [B,H,S,DK]
// EPI 3: tanh(acc+bias[col]) -> kn tiles [B,H][kt:16][prow:128][64], pi+XOR
// EPI 1: acc+bias[row] -> vt tiles [B,H][kt:16][dk:64][128], XOR
// EPI 2: acc+bias[col] -> fp32 merged [M,N]
// SWZ: XCD chunking (1: y-panels contiguous per XCD; 2: x-panels).
template <int EPI, int SWZ>
__global__ __launch_bounds__(256) void gemm_bt(const ushort_t* __restrict__ A,
                                               const ushort_t* __restrict__ B,
                                               const float* __restrict__ bias,
                                               void* __restrict__ outp,
                                               int Mdim, int Ndim, int Kdim,
                                               const float* __restrict__ temp) {
    __shared__ __align__(16) unsigned char As[2][16384];   // [buf][row:128][128B]
    __shared__ __align__(16) unsigned char Bs[2][16384];

    int bx = blockIdx.x, by = blockIdx.y;
    if constexpr (SWZ != 0) {
        int nwg = gridDim.x * gridDim.y;
        int L = by * gridDim.x + bx;
        int cpx = nwg >> 3;
        int orig = (L & 7) * cpx + (L >> 3);
        if constexpr (SWZ == 1) { bx = orig % gridDim.x; by = orig / gridDim.x; }
        else                    { by = orig % gridDim.y; bx = orig / gridDim.y; }
    }

    const int tid = threadIdx.x, lane = tid & 63, wave = tid >> 6;
    const int wr = wave >> 1, wc = wave & 1;
    const int q = lane & 15, g = lane >> 4;
    const int m0 = by * 128, n0 = bx * 128;

    // staging: instr i covers tile rows (wave*4+i)*8 + (lane>>3),
    // col elems (lane&7)*8 — LDS dest (wave*4+i)*1024 + lane*16 (linear).
    const int strow = lane >> 3, stcol = (lane & 7) * 8;
    const ushort_t* Ab = A + (size_t)(m0 + strow) * Kdim + stcol;
    const ushort_t* Bb = B + (size_t)(n0 + strow) * Kdim + stcol;

    f32x4 acc[4][4] = {};
    const int nK = Kdim >> 6;

    // prologue: stage tile 0 into buffer 0
#pragma unroll
    for (int i = 0; i < 4; ++i) {
        const int ro = (wave * 4 + i) * 8;
        gl16(Ab + (size_t)ro * Kdim, As[0] + (wave * 4 + i) * 1024);
        gl16(Bb + (size_t)ro * Kdim, Bs[0] + (wave * 4 + i) * 1024);
    }
    __syncthreads();

    for (int kt = 0; kt < nK; ++kt) {
        const int cur = kt & 1;
        if (kt + 1 < nK) {
            const int k1 = (kt + 1) << 6;
#pragma unroll
            for (int i = 0; i < 4; ++i) {
                const int ro = (wave * 4 + i) * 8;
                gl16(Ab + (size_t)ro * Kdim + k1, As[cur ^ 1] + (wave * 4 + i) * 1024);
                gl16(Bb + (size_t)ro * Kdim + k1, Bs[cur ^ 1] + (wave * 4 + i) * 1024);
            }
        }
#pragma unroll
        for (int s = 0; s < 2; ++s) {
            const int cb = s * 64 + g * 16;
            bf16x8 a[4], b[4];
#pragma unroll
            for (int m = 0; m < 4; ++m)
                a[m] = *(const bf16x8*)(As[cur] + (wr * 64 + m * 16 + q) * 128 + cb);
#pragma unroll
            for (int n = 0; n < 4; ++n)
                b[n] = *(const bf16x8*)(Bs[cur] + (wc * 64 + n * 16 + q) * 128 + cb);
#pragma unroll
            for (int m = 0; m < 4; ++m)
#pragma unroll
                for (int n = 0; n < 4; ++n)
                    acc[m][n] = mfma16(a[m], b[n], acc[m][n]);
        }
        __syncthreads();   // drains vmcnt (next buf staged) + all reads of cur done
    }

    // Epilogue. C/D layout: row=(lane>>4)*4+r, col=lane&15.
#pragma unroll
    for (int m = 0; m < 4; ++m)
#pragma unroll
        for (int n = 0; n < 4; ++n) {
            int gn = n0 + wc * 64 + n * 16 + q;
            float sc_h = 1.f;
            if constexpr (EPI == 0) {
                sc_h = 0.18033688011112042f * __builtin_amdgcn_rcpf(temp[gn >> 6]);
            }
#pragma unroll
            for (int r = 0; r < 4; ++r) {
                int gm = m0 + wr * 64 + m * 16 + (g << 2) + r;
                float v = acc[m][n][r];
                if constexpr (EPI == 0) {
                    v = tanhf(v + bias[gn]) * sc_h;
                    int b = gm >> 11, s = gm & 2047, hh = gn >> 6, dk = gn & 63;
                    ((unsigned short*)outp)[(((size_t)(b * Hc + hh)) * Sc + s) * DKc + dk] = f2bf(v);
                } else if constexpr (EPI == 3) {
                    v = tanhf(v + bias[gn]);
                    int b = gm >> 11, s = gm & 2047, hh = gn >> 6, dk = gn & 63;
                    int kt2 = s >> 7, nr = s & 127;
                    int prow = (nr & 64) | (((nr >> 5) & 1) << 4) | (((nr >> 3) & 3) << 2)
                             | (((nr >> 2) & 1) << 5) | (nr & 3);
                    int eofs = ((dk * 2) ^ ((prow & 7) << 4)) >> 1;
                    size_t idx = ((size_t)(b * Hc + hh)) * Sc * DKc + (size_t)kt2 * 8192 + prow * 64 + eofs;
                    ((unsigned short*)outp)[idx] = f2bf(v);
                } else if constexpr (EPI == 1) {
                    v += bias[gm];
                    int hh = gm >> 6, dk = gm & 63, b = gn >> 11, s = gn & 2047;
                    int kt2 = s >> 7, kloc = s & 127;
                    int eofs = ((kloc * 2) ^ ((dk & 7) << 4)) >> 1;
                    size_t idx = ((size_t)(b * Hc + hh)) * Sc * DKc + (size_t)kt2 * 8192 + dk * 128 + eofs;
                    ((unsigned short*)outp)[idx] = f2bf(v);
                } else {
                    v += bias[gn];
                    ((float*)outp)[(size_t)gm * Ndim + gn] = v;
                }
            }
        }
}

// ---------------------------------------------------------------------------
// Flash attention (unchanged — issue-saturated at MfmaUtil+VALUBusy ~92%).
__global__ __launch_bounds__(512, 2) void attn_k(const ushort_t* __restrict__ qn,
                                                 const ushort_t* __restrict__ kn,
                                                 const ushort_t* __restrict__ vtp,
                                                 const unsigned* __restrict__ mbits,
                                                 ushort_t* __restrict__ ctxb) {
    __shared__ __align__(16) unsigned char Kl[2][16384];   // [buf][prow:128][128B swz]
    __shared__ __align__(16) unsigned char Vl[2][16384];   // [buf][dk:64][256B swz]

    const int tid = threadIdx.x, lane = tid & 63, wave = tid >> 6;
    const int q = lane & 15, g = lane >> 4;

    const int wg = blockIdx.x;
    const int orig = (wg & 7) * 64 + (wg >> 3);
    const int qt = orig & 7, h = (orig >> 3) & 15, b = orig >> 7;
    const int q0 = qt * 256;
    const int qr0 = q0 + wave * 32 + q;
    const size_t headoff = ((size_t)(b * Hc + h)) * Sc * DKc;

    const unsigned char* Ksrc = (const unsigned char*)(kn + headoff);
    const unsigned char* Vsrc = (const unsigned char*)(vtp + headoff);
    const int so = wave * 1024 + lane * 16;
    const int ld = wave * 1024;

    bf16x8 qf[2][2];
    {
        const ushort_t* p0 = qn + headoff + (size_t)qr0 * DKc + g * 8;
        qf[0][0] = *(const bf16x8*)p0;
        qf[0][1] = *(const bf16x8*)(p0 + 32);
        qf[1][0] = *(const bf16x8*)(p0 + 16 * DKc);
        qf[1][1] = *(const bf16x8*)(p0 + 16 * DKc + 32);
    }
    const unsigned* mr0 = mbits + ((size_t)b * Sc + qr0) * (Sc / 32);
    const unsigned* mr1 = mr0 + 16 * (Sc / 32);

    bf16x8 ones;
#pragma unroll
    for (int i = 0; i < 8; ++i) ones[i] = (__bf16)1.0f;

    f32x4 ctxa[2][4] = {};
    f32x4 lacc[2] = {};
    const int swz = (q & 7) << 4;
    const int sh = g << 2;

    gl16(Ksrc + so,        &Kl[0][ld]);
    gl16(Ksrc + 8192 + so, &Kl[0][8192 + ld]);
    gl16(Vsrc + so,        &Vl[0][ld]);
    gl16(Vsrc + 8192 + so, &Vl[0][8192 + ld]);
    __syncthreads();

    for (int kt = 0; kt < Sc / 128; ++kt) {
        const int cur = kt & 1;
        if (kt < Sc / 128 - 1) {
            const unsigned char* ks = Ksrc + (kt + 1) * 16384;
            const unsigned char* vs = Vsrc + (kt + 1) * 16384;
            gl16(ks + so,        &Kl[cur ^ 1][ld]);
            gl16(ks + 8192 + so, &Kl[cur ^ 1][8192 + ld]);
            gl16(vs + so,        &Vl[cur ^ 1][ld]);
            gl16(vs + 8192 + so, &Vl[cur ^ 1][8192 + ld]);
        }
        unsigned mwq[2][4];
        {
            uint4 t0 = *(const uint4*)(mr0 + kt * 4);
            uint4 t1 = *(const uint4*)(mr1 + kt * 4);
            mwq[0][0] = t0.x >> sh; mwq[0][1] = t0.y >> sh;
            mwq[0][2] = t0.z >> sh; mwq[0][3] = t0.w >> sh;
            mwq[1][0] = t1.x >> sh; mwq[1][1] = t1.y >> sh;
            mwq[1][2] = t1.z >> sh; mwq[1][3] = t1.w >> sh;
        }
        const unsigned char* Kb = Kl[cur];
        const unsigned char* Vb = Vl[cur];

#pragma unroll
        for (int kh = 0; kh < 2; ++kh) {
            f32x4 s0[4] = {}, s1[4] = {};
            __builtin_amdgcn_s_setprio(1);
#pragma unroll
            for (int f = 0; f < 4; ++f) {
                const int ro = (kh * 64 + f * 16 + q) * 128;
                bf16x8 a0 = *(const bf16x8*)(Kb + ro + ((g * 16) ^ swz));
                bf16x8 a1 = *(const bf16x8*)(Kb + ro + ((64 + g * 16) ^ swz));
                s0[f] = mfma16(a0, qf[0][0], s0[f]);
                s0[f] = mfma16(a1, qf[0][1], s0[f]);
                s1[f] = mfma16(a0, qf[1][0], s1[f]);
                s1[f] = mfma16(a1, qf[1][1], s1[f]);
            }
            __builtin_amdgcn_s_setprio(0);

#pragma unroll
            for (int f = 0; f < 4; ++f) {
                unsigned w0 = mwq[0][kh * 2 + (f >> 1)];
                unsigned w1 = mwq[1][kh * 2 + (f >> 1)];
#pragma unroll
                for (int r = 0; r < 4; ++r) {
                    const unsigned bitc = 1u << (((f & 1) << 4) + r);
                    float v0 = (w0 & bitc) ? s0[f][r] : -1e30f;
                    float v1 = (w1 & bitc) ? s1[f][r] : -1e30f;
                    s0[f][r] = __builtin_amdgcn_exp2f(v0);
                    s1[f][r] = __builtin_amdgcn_exp2f(v1);
                }
            }

            bf16x8 pa0[2], pa1[2];
#pragma unroll
            for (int cs = 0; cs < 2; ++cs)
#pragma unroll
                for (int r = 0; r < 4; ++r) {
                    pa0[cs][r]     = (__bf16)s0[cs][r];
                    pa0[cs][4 + r] = (__bf16)s0[cs + 2][r];
                    pa1[cs][r]     = (__bf16)s1[cs][r];
                    pa1[cs][4 + r] = (__bf16)s1[cs + 2][r];
                }

            __builtin_amdgcn_s_setprio(1);
#pragma unroll
            for (int cs = 0; cs < 2; ++cs) {
                const int csg = kh * 2 + cs;
                lacc[0] = mfma16(pa0[cs], ones, lacc[0]);
                lacc[1] = mfma16(pa1[cs], ones, lacc[1]);
#pragma unroll
                for (int j = 0; j < 4; ++j) {
                    bf16x8 vb = *(const bf16x8*)(Vb + (j * 16 + q) * 256 + ((csg * 64 + g * 16) ^ swz));
                    ctxa[0][j] = mfma16(pa0[cs], vb, ctxa[0][j]);
                    ctxa[1][j] = mfma16(pa1[cs], vb, ctxa[1][j]);
                }
            }
            __builtin_amdgcn_s_setprio(0);
        }
        __syncthreads();
    }

#pragma unroll
    for (int qg = 0; qg < 2; ++qg) {
        f32x4 linv;
#pragma unroll
        for (int r = 0; r < 4; ++r) linv[r] = __builtin_amdgcn_rcpf(lacc[qg][r]);
#pragma unroll
        for (int j = 0; j < 4; ++j)
#pragma unroll
            for (int r = 0; r < 4; ++r) {
                int srow = q0 + wave * 32 + qg * 16 + (g << 2) + r;
                int col = h * DKc + j * 16 + q;
                float v = ctxa[qg][j][r] * linv[r];
                ctxb[((size_t)b * Sc + srow) * Dc + col] = __builtin_bit_cast(unsigned short, (__bf16)v);
            }
    }
}

// ---------------------------------------------------------------------------
__global__ __launch_bounds__(256) void rmsnorm_k(float* __restrict__ out,
                                                 const float* __restrict__ w) {
    const int row = blockIdx.x, tid = threadIdx.x;
    float4* p = (float4*)(out + (size_t)row * Dc) + tid;
    float4 v = *p;
    float ss = v.x * v.x + v.y * v.y + v.z * v.z + v.w * v.w;
#pragma unroll
    for (int o = 32; o >= 1; o >>= 1) ss += __shfl_xor(ss, o);
    __shared__ float sm[4];
    if ((tid & 63) == 0) sm[tid >> 6] = ss;
    __syncthreads();
    float tot = sm[0] + sm[1] + sm[2] + sm[3];
    float r = rsqrtf(tot * (1.f / Dc) + 1e-8f);
    float4 wv = *((const float4*)w + tid);
    v.x *= r * wv.x; v.y *= r * wv.y; v.z *= r * wv.z; v.w *= r * wv.w;
    *p = v;
}

// ---------------------------------------------------------------------------
extern "C" void kernel_launch(void* const* d_in, const int* in_sizes, int n_in,
                              void* d_out, int out_size, void* d_ws, size_t ws_size,
                              hipStream_t stream) {
    (void)in_sizes; (void)n_in; (void)out_size; (void)ws_size;
    const float* Q    = (const float*)d_in[0];
    const float* K    = (const float*)d_in[1];
    const float* V    = (const float*)d_in[2];
    const int*   mask = (const int*)  d_in[3];
    const float* wq   = (const float*)d_in[4];
    const float* bq   = (const float*)d_in[5];
    const float* wk   = (const float*)d_in[6];
    const float* bk   = (const float*)d_in[7];
    const float* wv   = (const float*)d_in[8];
    const float* bv   = (const float*)d_in[9];
    const float* wo   = (const float*)d_in[10];
    const float* bo   = (const float*)d_in[11];
    const float* naqw = (const float*)d_in[12];
    const float* naqb = (const float*)d_in[13];
    const float* nakw = (const float*)d_in[14];
    const float* nakb = (const float*)d_in[15];
    const float* temp = (const float*)d_in[16];
    const float* rmsw = (const float*)d_in[17];

    char* ws = (char*)d_ws;
    size_t off = 0;
    auto take = [&](size_t n) { char* p = ws + off; off += (n + 255) & ~(size_t)255; return p; };
    unsigned short* vtb  = (unsigned short*)take((size_t)Mc * Dc * 2);
    unsigned short* qb   = (unsigned short*)take((size_t)Mc * Dc * 2);
    unsigned short* kb   = (unsigned short*)take((size_t)Mc * Dc * 2);
    unsigned short* vb   = (unsigned short*)take((size_t)Mc * Dc * 2);
    unsigned short* wqf  = (unsigned short*)take((size_t)Dc * Dc * 2);
    unsigned short* wkf  = (unsigned short*)take((size_t)Dc * Dc * 2);
    unsigned short* wvf  = (unsigned short*)take((size_t)Dc * Dc * 2);
    unsigned short* wof  = (unsigned short*)take((size_t)Dc * Dc * 2);
    float*    bqf   = (float*)take(Dc * 4);
    float*    bkf   = (float*)take(Dc * 4);
    unsigned* mbits = (unsigned*)take((size_t)Bc * Sc * (Sc / 32) * 4);
    // aliases (live ranges disjoint, each fully rewritten every call):
    unsigned short* qnb  = vb;   // vb dead after vt GEMM; qn GEMM runs after
    unsigned short* knb  = qb;   // qb dead after qn GEMM; kn GEMM runs after
    unsigned short* ctxb = kb;   // kb dead after kn GEMM; attn runs after

    fold_w2<<<dim3(4, 16, 3), 256, 0, stream>>>(naqw, wq, wqf, nakw, wk, wkf,
                                                bq, naqb, bqf, bk, nakb, bkf);
    conv_all<<<dim3((3 * Mc * Dc + 2 * Dc * Dc) / 8 / 256), 256, 0, stream>>>(
        Q, K, V, wv, wo, qb, kb, vb, wvf, wof);
    pack_mask<<<dim3(Bc * Sc * Sc / 256), 256, 0, stream>>>(mask, mbits);

    // v^T = Wv @ V^T + bv   (tile layout for attn staging)
    gemm_bt<1, 2><<<dim3(Mc / 128, Dc / 128), 256, 0, stream>>>(
        wvf, vb, bv, vtb, Dc, Mc, Dc, nullptr);
    // qn = tanh(Qb @ Wq'^T + bq') * log2e/(8*temp[h])
    gemm_bt<0, 1><<<dim3(Dc / 128, Mc / 128), 256, 0, stream>>>(
        qb, wqf, bqf, qnb, Mc, Dc, Dc, temp);
    // kn = tanh(Kb @ Wk'^T + bk')  (tile layout, pi-permuted rows, XOR swz)
    gemm_bt<3, 1><<<dim3(Dc / 128, Mc / 128), 256, 0, stream>>>(
        kb, wkf, bkf, knb, Mc, Dc, Dc, nullptr);

    attn_k<<<dim3(512), 512, 0, stream>>>(qnb, knb, vtb, mbits, ctxb);

    // out = ctx @ wo^T + bo (fp32 into d_out), then in-place RMSNorm
    gemm_bt<2, 1><<<dim3(Dc / 128, Mc / 128), 256, 0, stream>>>(
        ctxb, wof, bo, d_out, Mc, Dc, Dc, nullptr);
    rmsnorm_k<<<dim3(Mc), 256, 0, stream>>>((float*)d_out, rmsw);
}